// Round 8
// baseline (244.172 us; speedup 1.0000x reference)
//
#include <hip/hip_runtime.h>
#include <hip/hip_fp16.h>

#define N_NODES 100000
#define N_EDGES 1600000
#define IN_C 64
#define HID_C 64
#define OUT_C 16

#define BKT 256        // nodes per dst bucket
#define BSH 8          // dst >> 8 = bucket
#define NBKT 391       // ceil(100000/256)
#define GB 256         // blocks in edge-binning passes
#define EPB 6250       // edges per binning block (256*6250 = 1.6M exact)
#define LM (NBKT*GB)   // bucket count-matrix length = 100096
#define NBM ((LM + 255) / 256)  // 391 scan blocks

// ---------------------------------------------------------------------------
// Pass A1: per-block bucket histogram -> S[bucket*GB + block]. LDS only.
// ---------------------------------------------------------------------------
__global__ __launch_bounds__(256) void k_count(const int* __restrict__ dst,
                                               int* __restrict__ S) {
  __shared__ int h[NBKT];
  for (int i = threadIdx.x; i < NBKT; i += 256) h[i] = 0;
  __syncthreads();
  int base = blockIdx.x * EPB;
  int end = base + EPB;
  for (int e = base + threadIdx.x; e < end; e += 256)
    atomicAdd(&h[dst[e] >> BSH], 1);
  __syncthreads();
  for (int i = threadIdx.x; i < NBKT; i += 256) S[i * GB + blockIdx.x] = h[i];
}

// ---------------------------------------------------------------------------
// Generic 3-kernel exclusive scan (L=100096, nb=391)
// ---------------------------------------------------------------------------
__global__ __launch_bounds__(256) void gscan_a(const int* __restrict__ in,
                                               int* __restrict__ bsum, int L) {
  __shared__ int s[256];
  int i = blockIdx.x * 256 + threadIdx.x;
  s[threadIdx.x] = (i < L) ? in[i] : 0;
  __syncthreads();
  for (int st = 128; st > 0; st >>= 1) {
    if (threadIdx.x < st) s[threadIdx.x] += s[threadIdx.x + st];
    __syncthreads();
  }
  if (threadIdx.x == 0) bsum[blockIdx.x] = s[0];
}

__global__ __launch_bounds__(512) void gscan_b(int* __restrict__ bsum, int nb) {
  __shared__ int s[512];
  int t = threadIdx.x;
  int v = (t < nb) ? bsum[t] : 0;
  s[t] = v;
  __syncthreads();
  for (int st = 1; st < 512; st <<= 1) {
    int a = (t >= st) ? s[t - st] : 0;
    __syncthreads();
    s[t] += a;
    __syncthreads();
  }
  if (t < nb) bsum[t] = s[t] - v;  // exclusive
}

__global__ __launch_bounds__(256) void gscan_c(const int* __restrict__ in,
                                               const int* __restrict__ bsum,
                                               int* __restrict__ outEx, int L) {
  __shared__ int s[256];
  int t = threadIdx.x;
  int i = blockIdx.x * 256 + t;
  int v = (i < L) ? in[i] : 0;
  s[t] = v;
  __syncthreads();
  for (int st = 1; st < 256; st <<= 1) {
    int a = (t >= st) ? s[t - st] : 0;
    __syncthreads();
    s[t] += a;
    __syncthreads();
  }
  if (i < L) outEx[i] = s[t] - v + bsum[blockIdx.x];
}

// ---------------------------------------------------------------------------
// Pass A2: scatter edges into bucket-binned array (frontier writes are
// line-dense, L2-absorbed). Entry packs (src<<8)|dst_local.
// ---------------------------------------------------------------------------
__global__ __launch_bounds__(256) void k_binscatter(
    const int* __restrict__ src, const int* __restrict__ dst,
    const int* __restrict__ R, int* __restrict__ binned) {
  __shared__ int cur[NBKT];
  for (int i = threadIdx.x; i < NBKT; i += 256)
    cur[i] = R[i * GB + blockIdx.x];
  __syncthreads();
  int base = blockIdx.x * EPB;
  int end = base + EPB;
  for (int e = base + threadIdx.x; e < end; e += 256) {
    int d = dst[e];
    int pos = atomicAdd(&cur[d >> BSH], 1);
    binned[pos] = (src[e] << BSH) | (d & (BKT - 1));
  }
}

// ---------------------------------------------------------------------------
// Pass B (fused): per-bucket node histogram -> LDS exclusive scan ->
// rowstart/cnt -> scatter binned segment to CSR. No global atomics.
// ---------------------------------------------------------------------------
__global__ __launch_bounds__(256) void k_finalize(
    const int* __restrict__ binned, const int* __restrict__ R,
    int* __restrict__ csr, int* __restrict__ rowstart, int* __restrict__ cnt) {
  int b = blockIdx.x;
  __shared__ int hcnt[BKT];
  __shared__ int hscan[BKT];
  __shared__ int cur[BKT];
  int t = threadIdx.x;
  hcnt[t] = 0;
  __syncthreads();
  int start = R[b * GB];
  int end = (b == NBKT - 1) ? N_EDGES : R[(b + 1) * GB];
  for (int i = start + t; i < end; i += 256)
    atomicAdd(&hcnt[binned[i] & (BKT - 1)], 1);
  __syncthreads();
  int v = hcnt[t];
  hscan[t] = v;
  __syncthreads();
  for (int st = 1; st < 256; st <<= 1) {
    int a = (t >= st) ? hscan[t - st] : 0;
    __syncthreads();
    hscan[t] += a;
    __syncthreads();
  }
  int rs = start + hscan[t] - v;  // rowstart of node b*BKT + t
  cur[t] = rs;
  int n = (b << BSH) + t;
  if (n < N_NODES) {
    rowstart[n] = rs;
    cnt[n] = v;
  }
  __syncthreads();
  for (int i = start + t; i < end; i += 256) {
    int vv = binned[i];
    int pos = atomicAdd(&cur[vv & (BKT - 1)], 1);
    csr[pos] = vv >> BSH;
  }
}

// ---------------------------------------------------------------------------
// GEMM 1: p(fp16) = x @ Wl ; q(fp16) = x @ Wr + b   (M=100k, K=64, N=64+64)
// fp16 LDS for A and W: 24.7 KB total -> 6 blocks/CU (vs 3 at fp32).
// k processed in pairs via __half2. All LDS reads broadcast or 2-way.
// ---------------------------------------------------------------------------
__global__ __launch_bounds__(256) void k_gemm1(
    const float* __restrict__ x, const float* __restrict__ Wl,
    const float* __restrict__ Wr, const float* __restrict__ b,
    __half* __restrict__ p, __half* __restrict__ q) {
  __shared__ __half sAh[64 * 68];   // 8704 B, row stride 136 B (8B-aligned)
  __shared__ __half sWh[64 * 128];  // 16384 B: [k][0..63]=Wl, [k][64..127]=Wr
  int t = threadIdx.x;
  int n0 = blockIdx.x * 64;

  // stage A: fp32 global (float4) -> fp16 LDS (half4 via float2 store)
  for (int f = t; f < 1024; f += 256) {
    int r = f >> 4, c4 = f & 15;
    int n = n0 + r;
    float4 v = {0.0f, 0.0f, 0.0f, 0.0f};
    if (n < N_NODES) v = *(const float4*)&x[(size_t)n * 64 + c4 * 4];
    union { __half h[4]; float2 f2; } u;
    u.h[0] = __float2half(v.x); u.h[1] = __float2half(v.y);
    u.h[2] = __float2half(v.z); u.h[3] = __float2half(v.w);
    *(float2*)&sAh[r * 68 + c4 * 4] = u.f2;
  }
  // stage W: fp32 global -> fp16 LDS
  for (int f = t; f < 2048; f += 256) {
    int k = f >> 5, c4 = f & 31;
    float4 w = (c4 < 16) ? *(const float4*)&Wl[k * 64 + c4 * 4]
                         : *(const float4*)&Wr[k * 64 + (c4 - 16) * 4];
    union { __half h[4]; float2 f2; } u;
    u.h[0] = __float2half(w.x); u.h[1] = __float2half(w.y);
    u.h[2] = __float2half(w.z); u.h[3] = __float2half(w.w);
    *(float2*)&sWh[k * 128 + c4 * 4] = u.f2;
  }
  __syncthreads();

  int tx = t & 15;  // col quad
  int ty = t >> 4;  // node group
  float accL[4][4], accR[4][4];
#pragma unroll
  for (int i = 0; i < 4; ++i)
#pragma unroll
    for (int j = 0; j < 4; ++j) { accL[i][j] = 0.0f; accR[i][j] = 0.0f; }

  for (int k = 0; k < 64; k += 2) {
    float2 wl0r = *(float2*)&sWh[k * 128 + tx * 4];          // 4 cols, k
    float2 wl1r = *(float2*)&sWh[(k + 1) * 128 + tx * 4];    // 4 cols, k+1
    float2 wr0r = *(float2*)&sWh[k * 128 + 64 + tx * 4];
    float2 wr1r = *(float2*)&sWh[(k + 1) * 128 + 64 + tx * 4];
    const __half2* wl0h = (const __half2*)&wl0r;
    const __half2* wl1h = (const __half2*)&wl1r;
    const __half2* wr0h = (const __half2*)&wr0r;
    const __half2* wr1h = (const __half2*)&wr1r;
    float2 l0a = __half22float2(wl0h[0]), l0b = __half22float2(wl0h[1]);
    float2 l1a = __half22float2(wl1h[0]), l1b = __half22float2(wl1h[1]);
    float2 r0a = __half22float2(wr0h[0]), r0b = __half22float2(wr0h[1]);
    float2 r1a = __half22float2(wr1h[0]), r1b = __half22float2(wr1h[1]);
    float wl0[4] = {l0a.x, l0a.y, l0b.x, l0b.y};
    float wl1[4] = {l1a.x, l1a.y, l1b.x, l1b.y};
    float wr0[4] = {r0a.x, r0a.y, r0b.x, r0b.y};
    float wr1[4] = {r1a.x, r1a.y, r1b.x, r1b.y};
#pragma unroll
    for (int i = 0; i < 4; ++i) {
      __half2 a2 = *(__half2*)&sAh[(ty * 4 + i) * 68 + k];
      float2 fa = __half22float2(a2);
#pragma unroll
      for (int j = 0; j < 4; ++j) {
        accL[i][j] += fa.x * wl0[j] + fa.y * wl1[j];
        accR[i][j] += fa.x * wr0[j] + fa.y * wr1[j];
      }
    }
  }

  float4 bv = *(const float4*)&b[tx * 4];
#pragma unroll
  for (int i = 0; i < 4; ++i) {
    int n = n0 + ty * 4 + i;
    if (n >= N_NODES) break;
    int c = tx * 4;
    union { __half h[4]; float2 f; } up, uq;
#pragma unroll
    for (int j = 0; j < 4; ++j) up.h[j] = __float2half(accL[i][j]);
    uq.h[0] = __float2half(accR[i][0] + bv.x);
    uq.h[1] = __float2half(accR[i][1] + bv.y);
    uq.h[2] = __float2half(accR[i][2] + bv.z);
    uq.h[3] = __float2half(accR[i][3] + bv.w);
    *(float2*)&p[(size_t)n * 64 + c] = up.f;
    *(float2*)&q[(size_t)n * 64 + c] = uq.f;
  }
}

// ---------------------------------------------------------------------------
// Fuse 1: h[n] = relu(mean_j p1[csr_j] + q1[n]) in place over q1 (fp16).
// float4 gathers: 8 lanes per node (16B each = 128B row), 32 nodes/block.
// ---------------------------------------------------------------------------
__global__ __launch_bounds__(256) void k_fuse1(
    const float4* __restrict__ p1, const int* __restrict__ rowstart,
    const int* __restrict__ cnt, const int* __restrict__ csr,
    float4* __restrict__ q1h) {
  int t = threadIdx.x;
  int n = blockIdx.x * 32 + (t >> 3);  // 3125*32 = 100000 exact
  int c4 = t & 7;
  int row = rowstart[n];
  int deg = cnt[n];
  float acc[8];
#pragma unroll
  for (int m = 0; m < 8; ++m) acc[m] = 0.0f;
  int j = 0;
  for (; j + 4 <= deg; j += 4) {
    int s0 = csr[row + j];
    int s1 = csr[row + j + 1];
    int s2 = csr[row + j + 2];
    int s3 = csr[row + j + 3];
    float4 a0 = p1[s0 * 8 + c4];
    float4 a1 = p1[s1 * 8 + c4];
    float4 a2 = p1[s2 * 8 + c4];
    float4 a3 = p1[s3 * 8 + c4];
    const __half2* h0 = (const __half2*)&a0;
    const __half2* h1 = (const __half2*)&a1;
    const __half2* h2 = (const __half2*)&a2;
    const __half2* h3 = (const __half2*)&a3;
#pragma unroll
    for (int m = 0; m < 4; ++m) {
      float2 f0 = __half22float2(h0[m]);
      float2 f1 = __half22float2(h1[m]);
      float2 f2 = __half22float2(h2[m]);
      float2 f3 = __half22float2(h3[m]);
      acc[2 * m]     += (f0.x + f1.x) + (f2.x + f3.x);
      acc[2 * m + 1] += (f0.y + f1.y) + (f2.y + f3.y);
    }
  }
  for (; j < deg; ++j) {
    float4 a = p1[csr[row + j] * 8 + c4];
    const __half2* h = (const __half2*)&a;
#pragma unroll
    for (int m = 0; m < 4; ++m) {
      float2 f = __half22float2(h[m]);
      acc[2 * m] += f.x;
      acc[2 * m + 1] += f.y;
    }
  }
  float inv = 1.0f / fmaxf((float)deg, 1.0f);
  int o = n * 8 + c4;
  float4 qv = q1h[o];
  __half2* qh = (__half2*)&qv;
  float4 r;
  __half2* rh = (__half2*)&r;
#pragma unroll
  for (int m = 0; m < 4; ++m) {
    float2 f = __half22float2(qh[m]);
    float2 s;
    s.x = fmaxf(acc[2 * m] * inv + f.x, 0.0f);
    s.y = fmaxf(acc[2 * m + 1] * inv + f.y, 0.0f);
    rh[m] = __float22half2_rn(s);
  }
  q1h[o] = r;
}

// ---------------------------------------------------------------------------
// GEMM 2: p2(fp16) = h @ W2l ; q2(fp32) = h @ W2r + b2  (h is fp16)
// fp16 LDS (21.4 KB) -> 7 blocks/CU. h staged raw (no converts).
// ---------------------------------------------------------------------------
__global__ __launch_bounds__(256) void k_gemm2(
    const __half* __restrict__ h, const float* __restrict__ Wl,
    const float* __restrict__ Wr, const float* __restrict__ b,
    __half* __restrict__ p, float* __restrict__ q) {
  __shared__ __half sAh[128 * 68];  // 17408 B
  __shared__ __half sWh[64 * 32];   // 4096 B: [k][0..15]=W2l, [k][16..31]=W2r
  int t = threadIdx.x;
  int n0 = blockIdx.x * 128;

  for (int f = t; f < 128 * 16; f += 256) {  // half4 chunks
    int r = f >> 4, c4 = f & 15;
    int n = n0 + r;
    float2 v = {0.0f, 0.0f};
    if (n < N_NODES) v = *(const float2*)&h[(size_t)n * 64 + c4 * 4];
    *(float2*)&sAh[r * 68 + c4 * 4] = v;
  }
  for (int f = t; f < 512; f += 256) {
    int k = f >> 3, c4 = f & 7;
    float4 w = (c4 < 4) ? *(const float4*)&Wl[k * 16 + c4 * 4]
                        : *(const float4*)&Wr[k * 16 + (c4 - 4) * 4];
    union { __half h[4]; float2 f2; } u;
    u.h[0] = __float2half(w.x); u.h[1] = __float2half(w.y);
    u.h[2] = __float2half(w.z); u.h[3] = __float2half(w.w);
    *(float2*)&sWh[k * 32 + c4 * 4] = u.f2;
  }
  __syncthreads();

  int tx = t & 7;
  int ty = t >> 3;
  float acc[4][4];
#pragma unroll
  for (int i = 0; i < 4; ++i)
#pragma unroll
    for (int j = 0; j < 4; ++j) acc[i][j] = 0.0f;

  for (int k = 0; k < 64; k += 2) {
    float2 w0r = *(float2*)&sWh[k * 32 + tx * 4];
    float2 w1r = *(float2*)&sWh[(k + 1) * 32 + tx * 4];
    const __half2* w0h = (const __half2*)&w0r;
    const __half2* w1h = (const __half2*)&w1r;
    float2 a0 = __half22float2(w0h[0]), b0 = __half22float2(w0h[1]);
    float2 a1 = __half22float2(w1h[0]), b1f = __half22float2(w1h[1]);
    float w0[4] = {a0.x, a0.y, b0.x, b0.y};
    float w1[4] = {a1.x, a1.y, b1f.x, b1f.y};
#pragma unroll
    for (int i = 0; i < 4; ++i) {
      __half2 a2 = *(__half2*)&sAh[(ty * 4 + i) * 68 + k];
      float2 fa = __half22float2(a2);
#pragma unroll
      for (int j = 0; j < 4; ++j)
        acc[i][j] += fa.x * w0[j] + fa.y * w1[j];
    }
  }

#pragma unroll
  for (int i = 0; i < 4; ++i) {
    int n = n0 + ty * 4 + i;
    if (n >= N_NODES) break;
    if (tx < 4) {
      int c = tx * 4;
      union { __half h[4]; float2 f; } u;
#pragma unroll
      for (int j = 0; j < 4; ++j) u.h[j] = __float2half(acc[i][j]);
      *(float2*)&p[(size_t)n * 16 + c] = u.f;
    } else {
      int c = (tx - 4) * 4;
      float4 o = {acc[i][0] + b[c], acc[i][1] + b[c + 1], acc[i][2] + b[c + 2],
                  acc[i][3] + b[c + 3]};
      *(float4*)&q[(size_t)n * 16 + c] = o;
    }
  }
}

// ---------------------------------------------------------------------------
// Fuse 2: out[n] = mean_j p2[csr_j] + q2[n].
// float4 gathers: 2 lanes per node (16B each = 32B row), 128 nodes/block.
// ---------------------------------------------------------------------------
__global__ __launch_bounds__(256) void k_fuse2(
    const float4* __restrict__ p2, const float4* __restrict__ q2,
    const int* __restrict__ rowstart, const int* __restrict__ cnt,
    const int* __restrict__ csr, float4* __restrict__ out) {
  int t = threadIdx.x;
  int n = blockIdx.x * 128 + (t >> 1);
  if (n >= N_NODES) return;
  int c8 = t & 1;  // which 16B half of the 32B fp16 row
  int row = rowstart[n];
  int deg = cnt[n];
  float acc[8];
#pragma unroll
  for (int m = 0; m < 8; ++m) acc[m] = 0.0f;
  int j = 0;
  for (; j + 4 <= deg; j += 4) {
    int s0 = csr[row + j];
    int s1 = csr[row + j + 1];
    int s2 = csr[row + j + 2];
    int s3 = csr[row + j + 3];
    float4 a0 = p2[s0 * 2 + c8];
    float4 a1 = p2[s1 * 2 + c8];
    float4 a2 = p2[s2 * 2 + c8];
    float4 a3 = p2[s3 * 2 + c8];
    const __half2* h0 = (const __half2*)&a0;
    const __half2* h1 = (const __half2*)&a1;
    const __half2* h2 = (const __half2*)&a2;
    const __half2* h3 = (const __half2*)&a3;
#pragma unroll
    for (int m = 0; m < 4; ++m) {
      float2 f0 = __half22float2(h0[m]);
      float2 f1 = __half22float2(h1[m]);
      float2 f2 = __half22float2(h2[m]);
      float2 f3 = __half22float2(h3[m]);
      acc[2 * m]     += (f0.x + f1.x) + (f2.x + f3.x);
      acc[2 * m + 1] += (f0.y + f1.y) + (f2.y + f3.y);
    }
  }
  for (; j < deg; ++j) {
    float4 a = p2[csr[row + j] * 2 + c8];
    const __half2* h = (const __half2*)&a;
#pragma unroll
    for (int m = 0; m < 4; ++m) {
      float2 f = __half22float2(h[m]);
      acc[2 * m] += f.x;
      acc[2 * m + 1] += f.y;
    }
  }
  float inv = 1.0f / fmaxf((float)deg, 1.0f);
  float4 q0 = q2[n * 4 + c8 * 2];
  float4 q1v = q2[n * 4 + c8 * 2 + 1];
  float4 o0 = {acc[0] * inv + q0.x, acc[1] * inv + q0.y,
               acc[2] * inv + q0.z, acc[3] * inv + q0.w};
  float4 o1 = {acc[4] * inv + q1v.x, acc[5] * inv + q1v.y,
               acc[6] * inv + q1v.z, acc[7] * inv + q1v.w};
  out[n * 4 + c8 * 2] = o0;
  out[n * 4 + c8 * 2 + 1] = o1;
}

extern "C" void kernel_launch(void* const* d_in, const int* in_sizes, int n_in,
                              void* d_out, int out_size, void* d_ws, size_t ws_size,
                              hipStream_t stream) {
  const float* x   = (const float*)d_in[0];
  const int* edge  = (const int*)d_in[1];
  const int* src   = edge;            // edge_index[0]
  const int* dst   = edge + N_EDGES;  // edge_index[1]
  const float* W1l = (const float*)d_in[2];
  const float* b1  = (const float*)d_in[3];
  const float* W1r = (const float*)d_in[4];
  const float* W2l = (const float*)d_in[5];
  const float* b2  = (const float*)d_in[6];
  const float* W2r = (const float*)d_in[7];
  float* out = (float*)d_out;

  // workspace layout (4-byte units; p1 base is 16B aligned)
  int* S        = (int*)d_ws;          // LM = 100096 (bucket count matrix)
  int* bsum     = S + LM;              // 512
  int* R        = bsum + 512;          // LM (scanned bucket offsets)
  int* rowstart = R + LM;              // 100000
  int* cnt      = rowstart + N_NODES;  // 100000
  int* binned   = cnt + N_NODES;       // 1600000
  int* csr      = binned + N_EDGES;    // 1600000
  __half* p1    = (__half*)(csr + N_EDGES);    // 6.4M halves (12.8 MB)
  __half* q1h   = p1 + (size_t)N_NODES * 64;   // 6.4M halves (q1 -> h in place)
  __half* p2    = p1;                          // layer-2 reuse (p1 dead)
  float* q2     = (float*)(p1 + (size_t)N_NODES * 16);  // after p2 (3.2MB)

  // --- CSR build: 6 dispatches, no global atomics ---
  k_count<<<GB, 256, 0, stream>>>(dst, S);
  gscan_a<<<NBM, 256, 0, stream>>>(S, bsum, LM);
  gscan_b<<<1, 512, 0, stream>>>(bsum, NBM);
  gscan_c<<<NBM, 256, 0, stream>>>(S, bsum, R, LM);
  k_binscatter<<<GB, 256, 0, stream>>>(src, dst, R, binned);
  k_finalize<<<NBKT, 256, 0, stream>>>(binned, R, csr, rowstart, cnt);

  // --- layer 1 ---
  k_gemm1<<<(N_NODES + 63) / 64, 256, 0, stream>>>(x, W1l, W1r, b1, p1, q1h);
  k_fuse1<<<N_NODES / 32, 256, 0, stream>>>((const float4*)p1, rowstart, cnt,
                                            csr, (float4*)q1h);

  // --- layer 2 ---
  k_gemm2<<<(N_NODES + 127) / 128, 256, 0, stream>>>(q1h, W2l, W2r, b2, p2, q2);
  k_fuse2<<<(N_NODES + 127) / 128, 256, 0, stream>>>((const float4*)p2,
                                                     (const float4*)q2,
                                                     rowstart, cnt, csr,
                                                     (float4*)out);
}

// Round 9
// 211.658 us; speedup vs baseline: 1.1536x; 1.1536x over previous
//
#include <hip/hip_runtime.h>
#include <hip/hip_fp16.h>

#define N_NODES 100000
#define N_EDGES 1600000
#define IN_C 64
#define HID_C 64
#define OUT_C 16

#define BKT 256        // nodes per dst bucket
#define BSH 8          // dst >> 8 = bucket
#define NBKT 391       // ceil(100000/256)
#define GB 256         // blocks in edge-binning passes
#define EPB 6250       // edges per binning block (256*6250 = 1.6M exact)
#define LM (NBKT*GB)   // bucket count-matrix length = 100096
#define NBM ((LM + 255) / 256)  // 391 scan blocks

typedef _Float16 f16x8 __attribute__((ext_vector_type(8)));
typedef float f32x16 __attribute__((ext_vector_type(16)));

// ---------------------------------------------------------------------------
// Pass A1: per-block bucket histogram -> S[bucket*GB + block]. LDS only.
// ---------------------------------------------------------------------------
__global__ __launch_bounds__(256) void k_count(const int* __restrict__ dst,
                                               int* __restrict__ S) {
  __shared__ int h[NBKT];
  for (int i = threadIdx.x; i < NBKT; i += 256) h[i] = 0;
  __syncthreads();
  int base = blockIdx.x * EPB;
  int end = base + EPB;
  for (int e = base + threadIdx.x; e < end; e += 256)
    atomicAdd(&h[dst[e] >> BSH], 1);
  __syncthreads();
  for (int i = threadIdx.x; i < NBKT; i += 256) S[i * GB + blockIdx.x] = h[i];
}

// ---------------------------------------------------------------------------
// Generic 3-kernel exclusive scan (L=100096, nb=391)
// ---------------------------------------------------------------------------
__global__ __launch_bounds__(256) void gscan_a(const int* __restrict__ in,
                                               int* __restrict__ bsum, int L) {
  __shared__ int s[256];
  int i = blockIdx.x * 256 + threadIdx.x;
  s[threadIdx.x] = (i < L) ? in[i] : 0;
  __syncthreads();
  for (int st = 128; st > 0; st >>= 1) {
    if (threadIdx.x < st) s[threadIdx.x] += s[threadIdx.x + st];
    __syncthreads();
  }
  if (threadIdx.x == 0) bsum[blockIdx.x] = s[0];
}

__global__ __launch_bounds__(512) void gscan_b(int* __restrict__ bsum, int nb) {
  __shared__ int s[512];
  int t = threadIdx.x;
  int v = (t < nb) ? bsum[t] : 0;
  s[t] = v;
  __syncthreads();
  for (int st = 1; st < 512; st <<= 1) {
    int a = (t >= st) ? s[t - st] : 0;
    __syncthreads();
    s[t] += a;
    __syncthreads();
  }
  if (t < nb) bsum[t] = s[t] - v;  // exclusive
}

__global__ __launch_bounds__(256) void gscan_c(const int* __restrict__ in,
                                               const int* __restrict__ bsum,
                                               int* __restrict__ outEx, int L) {
  __shared__ int s[256];
  int t = threadIdx.x;
  int i = blockIdx.x * 256 + t;
  int v = (i < L) ? in[i] : 0;
  s[t] = v;
  __syncthreads();
  for (int st = 1; st < 256; st <<= 1) {
    int a = (t >= st) ? s[t - st] : 0;
    __syncthreads();
    s[t] += a;
    __syncthreads();
  }
  if (i < L) outEx[i] = s[t] - v + bsum[blockIdx.x];
}

// ---------------------------------------------------------------------------
// Pass A2: scatter edges into bucket-binned array. (src<<8)|dst_local.
// ---------------------------------------------------------------------------
__global__ __launch_bounds__(256) void k_binscatter(
    const int* __restrict__ src, const int* __restrict__ dst,
    const int* __restrict__ R, int* __restrict__ binned) {
  __shared__ int cur[NBKT];
  for (int i = threadIdx.x; i < NBKT; i += 256)
    cur[i] = R[i * GB + blockIdx.x];
  __syncthreads();
  int base = blockIdx.x * EPB;
  int end = base + EPB;
  for (int e = base + threadIdx.x; e < end; e += 256) {
    int d = dst[e];
    int pos = atomicAdd(&cur[d >> BSH], 1);
    binned[pos] = (src[e] << BSH) | (d & (BKT - 1));
  }
}

// ---------------------------------------------------------------------------
// Pass B (fused): per-bucket node histogram -> LDS exclusive scan ->
// rowstart/cnt -> scatter binned segment to CSR. No global atomics.
// ---------------------------------------------------------------------------
__global__ __launch_bounds__(256) void k_finalize(
    const int* __restrict__ binned, const int* __restrict__ R,
    int* __restrict__ csr, int* __restrict__ rowstart, int* __restrict__ cnt) {
  int b = blockIdx.x;
  __shared__ int hcnt[BKT];
  __shared__ int hscan[BKT];
  __shared__ int cur[BKT];
  int t = threadIdx.x;
  hcnt[t] = 0;
  __syncthreads();
  int start = R[b * GB];
  int end = (b == NBKT - 1) ? N_EDGES : R[(b + 1) * GB];
  for (int i = start + t; i < end; i += 256)
    atomicAdd(&hcnt[binned[i] & (BKT - 1)], 1);
  __syncthreads();
  int v = hcnt[t];
  hscan[t] = v;
  __syncthreads();
  for (int st = 1; st < 256; st <<= 1) {
    int a = (t >= st) ? hscan[t - st] : 0;
    __syncthreads();
    hscan[t] += a;
    __syncthreads();
  }
  int rs = start + hscan[t] - v;  // rowstart of node b*BKT + t
  cur[t] = rs;
  int n = (b << BSH) + t;
  if (n < N_NODES) {
    rowstart[n] = rs;
    cnt[n] = v;
  }
  __syncthreads();
  for (int i = start + t; i < end; i += 256) {
    int vv = binned[i];
    int pos = atomicAdd(&cur[vv & (BKT - 1)], 1);
    csr[pos] = vv >> BSH;
  }
}

// ---------------------------------------------------------------------------
// GEMM 1 (MFMA): p(fp16) = x @ Wl ; q(fp16) = x @ Wr + b
// Block = 64 rows x 128 cols. 4 waves: wave w -> rows (w&1)*32, cols (w>>1)*64.
// 32x32x16 f16 MFMA, K=64 in 4 chunks. sW stored transposed [col][k].
// A-frag: A[m=lane&31][k=(lane>>5)*8+j]; B-frag: B[k][n=lane&31] same k-map.
// C/D: col=lane&31, row=(reg&3)+4*(lane>>5)+8*(reg>>2).
// ---------------------------------------------------------------------------
__global__ __launch_bounds__(256) void k_gemm1(
    const float* __restrict__ x, const float* __restrict__ Wl,
    const float* __restrict__ Wr, const float* __restrict__ b,
    __half* __restrict__ p, __half* __restrict__ q) {
  __shared__ _Float16 sA[64 * 68];    // 8704 B  [row][k]
  __shared__ _Float16 sW[128 * 68];   // 17408 B [col][k] (transposed)
  int t = threadIdx.x;
  int n0 = blockIdx.x * 64;

  // stage A: fp32 global -> fp16 LDS (8B packed stores)
  for (int f = t; f < 1024; f += 256) {
    int r = f >> 4, c4 = f & 15;
    int n = n0 + r;
    float4 v = {0.0f, 0.0f, 0.0f, 0.0f};
    if (n < N_NODES) v = *(const float4*)&x[(size_t)n * 64 + c4 * 4];
    union { _Float16 h[4]; float2 f2; } u;
    u.h[0] = (_Float16)v.x; u.h[1] = (_Float16)v.y;
    u.h[2] = (_Float16)v.z; u.h[3] = (_Float16)v.w;
    *(float2*)&sA[r * 68 + c4 * 4] = u.f2;
  }
  // stage W transposed: [col][k]
  for (int f = t; f < 2048; f += 256) {
    int k = f >> 5, c4 = f & 31;
    float4 w = (c4 < 16) ? *(const float4*)&Wl[k * 64 + c4 * 4]
                         : *(const float4*)&Wr[k * 64 + (c4 - 16) * 4];
    int c = c4 * 4;
    sW[(c + 0) * 68 + k] = (_Float16)w.x;
    sW[(c + 1) * 68 + k] = (_Float16)w.y;
    sW[(c + 2) * 68 + k] = (_Float16)w.z;
    sW[(c + 3) * 68 + k] = (_Float16)w.w;
  }
  __syncthreads();

  int w = t >> 6, lane = t & 63;
  int m = lane & 31, half = lane >> 5;
  int rt = w & 1, cg = w >> 1;

  f32x16 acc[2];
#pragma unroll
  for (int r = 0; r < 16; ++r) { acc[0][r] = 0.0f; acc[1][r] = 0.0f; }

  const _Float16* pA = &sA[(rt * 32 + m) * 68 + half * 8];
  const _Float16* pB0 = &sW[(cg * 64 + m) * 68 + half * 8];
  const _Float16* pB1 = &sW[(cg * 64 + 32 + m) * 68 + half * 8];
#pragma unroll
  for (int kc = 0; kc < 4; ++kc) {
    union { f16x8 v; float2 f2[2]; } a, b0, b1;
    a.f2[0] = *(const float2*)(pA + kc * 16);
    a.f2[1] = *(const float2*)(pA + kc * 16 + 4);
    b0.f2[0] = *(const float2*)(pB0 + kc * 16);
    b0.f2[1] = *(const float2*)(pB0 + kc * 16 + 4);
    b1.f2[0] = *(const float2*)(pB1 + kc * 16);
    b1.f2[1] = *(const float2*)(pB1 + kc * 16 + 4);
    acc[0] = __builtin_amdgcn_mfma_f32_32x32x16_f16(a.v, b0.v, acc[0], 0, 0, 0);
    acc[1] = __builtin_amdgcn_mfma_f32_32x32x16_f16(a.v, b1.v, acc[1], 0, 0, 0);
  }

  if (cg == 0) {  // cols 0..63 -> p
#pragma unroll
    for (int tt = 0; tt < 2; ++tt) {
      int col = tt * 32 + m;
#pragma unroll
      for (int r = 0; r < 16; ++r) {
        int row = (r & 3) + 4 * half + 8 * (r >> 2);
        int n = n0 + rt * 32 + row;
        if (n < N_NODES) p[(size_t)n * 64 + col] = __float2half(acc[tt][r]);
      }
    }
  } else {  // cols 64..127 -> q (+bias)
    float bias[2] = {b[m], b[32 + m]};
#pragma unroll
    for (int tt = 0; tt < 2; ++tt) {
      int col = tt * 32 + m;
#pragma unroll
      for (int r = 0; r < 16; ++r) {
        int row = (r & 3) + 4 * half + 8 * (r >> 2);
        int n = n0 + rt * 32 + row;
        if (n < N_NODES)
          q[(size_t)n * 64 + col] = __float2half(acc[tt][r] + bias[tt]);
      }
    }
  }
}

// ---------------------------------------------------------------------------
// Fuse 1: h[n] = relu(mean_j p1[csr_j] + q1[n]) in place over q1 (fp16).
// float4 gathers: 8 lanes per node (16B each = 128B row), 32 nodes/block.
// ---------------------------------------------------------------------------
__global__ __launch_bounds__(256) void k_fuse1(
    const float4* __restrict__ p1, const int* __restrict__ rowstart,
    const int* __restrict__ cnt, const int* __restrict__ csr,
    float4* __restrict__ q1h) {
  int t = threadIdx.x;
  int n = blockIdx.x * 32 + (t >> 3);  // 3125*32 = 100000 exact
  int c4 = t & 7;
  int row = rowstart[n];
  int deg = cnt[n];
  float acc[8];
#pragma unroll
  for (int m = 0; m < 8; ++m) acc[m] = 0.0f;
  int j = 0;
  for (; j + 4 <= deg; j += 4) {
    int s0 = csr[row + j];
    int s1 = csr[row + j + 1];
    int s2 = csr[row + j + 2];
    int s3 = csr[row + j + 3];
    float4 a0 = p1[s0 * 8 + c4];
    float4 a1 = p1[s1 * 8 + c4];
    float4 a2 = p1[s2 * 8 + c4];
    float4 a3 = p1[s3 * 8 + c4];
    const __half2* h0 = (const __half2*)&a0;
    const __half2* h1 = (const __half2*)&a1;
    const __half2* h2 = (const __half2*)&a2;
    const __half2* h3 = (const __half2*)&a3;
#pragma unroll
    for (int m = 0; m < 4; ++m) {
      float2 f0 = __half22float2(h0[m]);
      float2 f1 = __half22float2(h1[m]);
      float2 f2 = __half22float2(h2[m]);
      float2 f3 = __half22float2(h3[m]);
      acc[2 * m]     += (f0.x + f1.x) + (f2.x + f3.x);
      acc[2 * m + 1] += (f0.y + f1.y) + (f2.y + f3.y);
    }
  }
  for (; j < deg; ++j) {
    float4 a = p1[csr[row + j] * 8 + c4];
    const __half2* h = (const __half2*)&a;
#pragma unroll
    for (int m = 0; m < 4; ++m) {
      float2 f = __half22float2(h[m]);
      acc[2 * m] += f.x;
      acc[2 * m + 1] += f.y;
    }
  }
  float inv = 1.0f / fmaxf((float)deg, 1.0f);
  int o = n * 8 + c4;
  float4 qv = q1h[o];
  __half2* qh = (__half2*)&qv;
  float4 r;
  __half2* rh = (__half2*)&r;
#pragma unroll
  for (int m = 0; m < 4; ++m) {
    float2 f = __half22float2(qh[m]);
    float2 s;
    s.x = fmaxf(acc[2 * m] * inv + f.x, 0.0f);
    s.y = fmaxf(acc[2 * m + 1] * inv + f.y, 0.0f);
    rh[m] = __float22half2_rn(s);
  }
  q1h[o] = r;
}

// ---------------------------------------------------------------------------
// GEMM 2 (MFMA): p2(fp16) = h @ W2l ; q2(fp32) = h @ W2r + b2
// Block = 128 rows x 32 cols. Wave w -> rows w*32, the single col-tile.
// ---------------------------------------------------------------------------
__global__ __launch_bounds__(256) void k_gemm2(
    const __half* __restrict__ h, const float* __restrict__ Wl,
    const float* __restrict__ Wr, const float* __restrict__ b,
    __half* __restrict__ p, float* __restrict__ q) {
  __shared__ _Float16 sA[128 * 68];  // 17408 B [row][k]
  __shared__ _Float16 sW[32 * 68];   // 4352 B  [col][k] (transposed)
  int t = threadIdx.x;
  int n0 = blockIdx.x * 128;

  for (int f = t; f < 2048; f += 256) {  // raw fp16 copy, 8B chunks
    int r = f >> 4, c4 = f & 15;
    int n = n0 + r;
    float2 v = {0.0f, 0.0f};
    if (n < N_NODES) v = *(const float2*)&h[(size_t)n * 64 + c4 * 4];
    *(float2*)&sA[r * 68 + c4 * 4] = v;
  }
  for (int f = t; f < 512; f += 256) {
    int k = f >> 3, c4 = f & 7;
    float4 w = (c4 < 4) ? *(const float4*)&Wl[k * 16 + c4 * 4]
                        : *(const float4*)&Wr[k * 16 + (c4 - 4) * 4];
    int c = c4 * 4;
    sW[(c + 0) * 68 + k] = (_Float16)w.x;
    sW[(c + 1) * 68 + k] = (_Float16)w.y;
    sW[(c + 2) * 68 + k] = (_Float16)w.z;
    sW[(c + 3) * 68 + k] = (_Float16)w.w;
  }
  __syncthreads();

  int w = t >> 6, lane = t & 63;
  int m = lane & 31, half = lane >> 5;

  f32x16 acc;
#pragma unroll
  for (int r = 0; r < 16; ++r) acc[r] = 0.0f;

  const _Float16* pA = &sA[(w * 32 + m) * 68 + half * 8];
  const _Float16* pB = &sW[m * 68 + half * 8];
#pragma unroll
  for (int kc = 0; kc < 4; ++kc) {
    union { f16x8 v; float2 f2[2]; } a, bb;
    a.f2[0] = *(const float2*)(pA + kc * 16);
    a.f2[1] = *(const float2*)(pA + kc * 16 + 4);
    bb.f2[0] = *(const float2*)(pB + kc * 16);
    bb.f2[1] = *(const float2*)(pB + kc * 16 + 4);
    acc = __builtin_amdgcn_mfma_f32_32x32x16_f16(a.v, bb.v, acc, 0, 0, 0);
  }

  if (m < 16) {  // cols 0..15 -> p2
#pragma unroll
    for (int r = 0; r < 16; ++r) {
      int row = (r & 3) + 4 * half + 8 * (r >> 2);
      int n = n0 + w * 32 + row;
      if (n < N_NODES) p[(size_t)n * 16 + m] = __float2half(acc[r]);
    }
  } else {  // cols 16..31 -> q2 (+bias)
    float bias = b[m - 16];
#pragma unroll
    for (int r = 0; r < 16; ++r) {
      int row = (r & 3) + 4 * half + 8 * (r >> 2);
      int n = n0 + w * 32 + row;
      if (n < N_NODES) q[(size_t)n * 16 + (m - 16)] = acc[r] + bias;
    }
  }
}

// ---------------------------------------------------------------------------
// Fuse 2: out[n] = mean_j p2[csr_j] + q2[n].
// float4 gathers: 2 lanes per node (16B each = 32B row), 128 nodes/block.
// ---------------------------------------------------------------------------
__global__ __launch_bounds__(256) void k_fuse2(
    const float4* __restrict__ p2, const float4* __restrict__ q2,
    const int* __restrict__ rowstart, const int* __restrict__ cnt,
    const int* __restrict__ csr, float4* __restrict__ out) {
  int t = threadIdx.x;
  int n = blockIdx.x * 128 + (t >> 1);
  if (n >= N_NODES) return;
  int c8 = t & 1;  // which 16B half of the 32B fp16 row
  int row = rowstart[n];
  int deg = cnt[n];
  float acc[8];
#pragma unroll
  for (int m = 0; m < 8; ++m) acc[m] = 0.0f;
  int j = 0;
  for (; j + 4 <= deg; j += 4) {
    int s0 = csr[row + j];
    int s1 = csr[row + j + 1];
    int s2 = csr[row + j + 2];
    int s3 = csr[row + j + 3];
    float4 a0 = p2[s0 * 2 + c8];
    float4 a1 = p2[s1 * 2 + c8];
    float4 a2 = p2[s2 * 2 + c8];
    float4 a3 = p2[s3 * 2 + c8];
    const __half2* h0 = (const __half2*)&a0;
    const __half2* h1 = (const __half2*)&a1;
    const __half2* h2 = (const __half2*)&a2;
    const __half2* h3 = (const __half2*)&a3;
#pragma unroll
    for (int m = 0; m < 4; ++m) {
      float2 f0 = __half22float2(h0[m]);
      float2 f1 = __half22float2(h1[m]);
      float2 f2 = __half22float2(h2[m]);
      float2 f3 = __half22float2(h3[m]);
      acc[2 * m]     += (f0.x + f1.x) + (f2.x + f3.x);
      acc[2 * m + 1] += (f0.y + f1.y) + (f2.y + f3.y);
    }
  }
  for (; j < deg; ++j) {
    float4 a = p2[csr[row + j] * 2 + c8];
    const __half2* h = (const __half2*)&a;
#pragma unroll
    for (int m = 0; m < 4; ++m) {
      float2 f = __half22float2(h[m]);
      acc[2 * m] += f.x;
      acc[2 * m + 1] += f.y;
    }
  }
  float inv = 1.0f / fmaxf((float)deg, 1.0f);
  float4 q0 = q2[n * 4 + c8 * 2];
  float4 q1v = q2[n * 4 + c8 * 2 + 1];
  float4 o0 = {acc[0] * inv + q0.x, acc[1] * inv + q0.y,
               acc[2] * inv + q0.z, acc[3] * inv + q0.w};
  float4 o1 = {acc[4] * inv + q1v.x, acc[5] * inv + q1v.y,
               acc[6] * inv + q1v.z, acc[7] * inv + q1v.w};
  out[n * 4 + c8 * 2] = o0;
  out[n * 4 + c8 * 2 + 1] = o1;
}

extern "C" void kernel_launch(void* const* d_in, const int* in_sizes, int n_in,
                              void* d_out, int out_size, void* d_ws, size_t ws_size,
                              hipStream_t stream) {
  const float* x   = (const float*)d_in[0];
  const int* edge  = (const int*)d_in[1];
  const int* src   = edge;            // edge_index[0]
  const int* dst   = edge + N_EDGES;  // edge_index[1]
  const float* W1l = (const float*)d_in[2];
  const float* b1  = (const float*)d_in[3];
  const float* W1r = (const float*)d_in[4];
  const float* W2l = (const float*)d_in[5];
  const float* b2  = (const float*)d_in[6];
  const float* W2r = (const float*)d_in[7];
  float* out = (float*)d_out;

  // workspace layout (4-byte units; p1 base is 16B aligned)
  int* S        = (int*)d_ws;          // LM = 100096 (bucket count matrix)
  int* bsum     = S + LM;              // 512
  int* R        = bsum + 512;          // LM (scanned bucket offsets)
  int* rowstart = R + LM;              // 100000
  int* cnt      = rowstart + N_NODES;  // 100000
  int* binned   = cnt + N_NODES;       // 1600000
  int* csr      = binned + N_EDGES;    // 1600000
  __half* p1    = (__half*)(csr + N_EDGES);    // 6.4M halves (12.8 MB)
  __half* q1h   = p1 + (size_t)N_NODES * 64;   // 6.4M halves (q1 -> h in place)
  __half* p2    = p1;                          // layer-2 reuse (p1 dead)
  float* q2     = (float*)(p1 + (size_t)N_NODES * 16);  // after p2 (3.2MB)

  // --- CSR build: 6 dispatches, no global atomics ---
  k_count<<<GB, 256, 0, stream>>>(dst, S);
  gscan_a<<<NBM, 256, 0, stream>>>(S, bsum, LM);
  gscan_b<<<1, 512, 0, stream>>>(bsum, NBM);
  gscan_c<<<NBM, 256, 0, stream>>>(S, bsum, R, LM);
  k_binscatter<<<GB, 256, 0, stream>>>(src, dst, R, binned);
  k_finalize<<<NBKT, 256, 0, stream>>>(binned, R, csr, rowstart, cnt);

  // --- layer 1 ---
  k_gemm1<<<(N_NODES + 63) / 64, 256, 0, stream>>>(x, W1l, W1r, b1, p1, q1h);
  k_fuse1<<<N_NODES / 32, 256, 0, stream>>>((const float4*)p1, rowstart, cnt,
                                            csr, (float4*)q1h);

  // --- layer 2 ---
  k_gemm2<<<(N_NODES + 127) / 128, 256, 0, stream>>>(q1h, W2l, W2r, b2, p2, q2);
  k_fuse2<<<(N_NODES + 127) / 128, 256, 0, stream>>>((const float4*)p2,
                                                     (const float4*)q2,
                                                     rowstart, cnt, csr,
                                                     (float4*)out);
}

// Round 10
// 203.635 us; speedup vs baseline: 1.1991x; 1.0394x over previous
//
#include <hip/hip_runtime.h>
#include <hip/hip_fp16.h>

#define N_NODES 100000
#define N_EDGES 1600000
#define IN_C 64
#define HID_C 64
#define OUT_C 16

#define BKT 256        // nodes per dst bucket
#define BSH 8          // dst >> 8 = bucket
#define NBKT 391       // ceil(100000/256)
#define GB 512         // blocks in edge-binning passes
#define EPB 3125       // edges per binning block (512*3125 = 1.6M exact)
#define LM (NBKT*GB)   // bucket count-matrix length = 200192
#define NBM ((LM + 255) / 256)  // 782 scan blocks

typedef _Float16 f16x8 __attribute__((ext_vector_type(8)));
typedef float f32x16 __attribute__((ext_vector_type(16)));

// ---------------------------------------------------------------------------
// Pass A1: per-block bucket histogram -> S[bucket*GB + block]. LDS only.
// ---------------------------------------------------------------------------
__global__ __launch_bounds__(512) void k_count(const int* __restrict__ dst,
                                               int* __restrict__ S) {
  __shared__ int h[NBKT];
  for (int i = threadIdx.x; i < NBKT; i += 512) h[i] = 0;
  __syncthreads();
  int base = blockIdx.x * EPB;
  int end = base + EPB;
  for (int e = base + threadIdx.x; e < end; e += 512)
    atomicAdd(&h[dst[e] >> BSH], 1);
  __syncthreads();
  for (int i = threadIdx.x; i < NBKT; i += 512) S[i * GB + blockIdx.x] = h[i];
}

// ---------------------------------------------------------------------------
// Generic 3-kernel exclusive scan (L=200192, nb=782)
// ---------------------------------------------------------------------------
__global__ __launch_bounds__(256) void gscan_a(const int* __restrict__ in,
                                               int* __restrict__ bsum, int L) {
  __shared__ int s[256];
  int i = blockIdx.x * 256 + threadIdx.x;
  s[threadIdx.x] = (i < L) ? in[i] : 0;
  __syncthreads();
  for (int st = 128; st > 0; st >>= 1) {
    if (threadIdx.x < st) s[threadIdx.x] += s[threadIdx.x + st];
    __syncthreads();
  }
  if (threadIdx.x == 0) bsum[blockIdx.x] = s[0];
}

__global__ __launch_bounds__(1024) void gscan_b(int* __restrict__ bsum, int nb) {
  __shared__ int s[1024];
  int t = threadIdx.x;
  int v = (t < nb) ? bsum[t] : 0;
  s[t] = v;
  __syncthreads();
  for (int st = 1; st < 1024; st <<= 1) {
    int a = (t >= st) ? s[t - st] : 0;
    __syncthreads();
    s[t] += a;
    __syncthreads();
  }
  if (t < nb) bsum[t] = s[t] - v;  // exclusive
}

__global__ __launch_bounds__(256) void gscan_c(const int* __restrict__ in,
                                               const int* __restrict__ bsum,
                                               int* __restrict__ outEx, int L) {
  __shared__ int s[256];
  int t = threadIdx.x;
  int i = blockIdx.x * 256 + t;
  int v = (i < L) ? in[i] : 0;
  s[t] = v;
  __syncthreads();
  for (int st = 1; st < 256; st <<= 1) {
    int a = (t >= st) ? s[t - st] : 0;
    __syncthreads();
    s[t] += a;
    __syncthreads();
  }
  if (i < L) outEx[i] = s[t] - v + bsum[blockIdx.x];
}

// ---------------------------------------------------------------------------
// Pass A2: scatter edges into bucket-binned array. (src<<8)|dst_local.
// ---------------------------------------------------------------------------
__global__ __launch_bounds__(512) void k_binscatter(
    const int* __restrict__ src, const int* __restrict__ dst,
    const int* __restrict__ R, int* __restrict__ binned) {
  __shared__ int cur[NBKT];
  for (int i = threadIdx.x; i < NBKT; i += 512)
    cur[i] = R[i * GB + blockIdx.x];
  __syncthreads();
  int base = blockIdx.x * EPB;
  int end = base + EPB;
  for (int e = base + threadIdx.x; e < end; e += 512) {
    int d = dst[e];
    int pos = atomicAdd(&cur[d >> BSH], 1);
    binned[pos] = (src[e] << BSH) | (d & (BKT - 1));
  }
}

// ---------------------------------------------------------------------------
// Pass B (fused): per-bucket node histogram -> LDS exclusive scan ->
// rowstart/cnt -> scatter binned segment to CSR. No global atomics.
// ---------------------------------------------------------------------------
__global__ __launch_bounds__(512) void k_finalize(
    const int* __restrict__ binned, const int* __restrict__ R,
    int* __restrict__ csr, int* __restrict__ rowstart, int* __restrict__ cnt) {
  int b = blockIdx.x;
  __shared__ int hcnt[BKT];
  __shared__ int hscan[BKT];
  __shared__ int cur[BKT];
  int t = threadIdx.x;
  if (t < BKT) hcnt[t] = 0;
  __syncthreads();
  int start = R[b * GB];
  int end = (b == NBKT - 1) ? N_EDGES : R[(b + 1) * GB];
  for (int i = start + t; i < end; i += 512)
    atomicAdd(&hcnt[binned[i] & (BKT - 1)], 1);
  __syncthreads();
  int v = 0;
  if (t < BKT) {
    v = hcnt[t];
    hscan[t] = v;
  }
  __syncthreads();
  for (int st = 1; st < 256; st <<= 1) {
    int a = 0;
    if (t < BKT && t >= st) a = hscan[t - st];
    __syncthreads();
    if (t < BKT) hscan[t] += a;
    __syncthreads();
  }
  if (t < BKT) {
    int rs = start + hscan[t] - v;  // rowstart of node b*BKT + t
    cur[t] = rs;
    int n = (b << BSH) + t;
    if (n < N_NODES) {
      rowstart[n] = rs;
      cnt[n] = v;
    }
  }
  __syncthreads();
  for (int i = start + t; i < end; i += 512) {
    int vv = binned[i];
    int pos = atomicAdd(&cur[vv & (BKT - 1)], 1);
    csr[pos] = vv >> BSH;
  }
}

// ---------------------------------------------------------------------------
// GEMM 1 (MFMA): p(fp16) = x @ Wl ; q(fp16) = x @ Wr + b
// Block = 64 rows x 128 cols, 4 waves, 32x32x16 f16 MFMA.
// ---------------------------------------------------------------------------
__global__ __launch_bounds__(256) void k_gemm1(
    const float* __restrict__ x, const float* __restrict__ Wl,
    const float* __restrict__ Wr, const float* __restrict__ b,
    __half* __restrict__ p, __half* __restrict__ q) {
  __shared__ _Float16 sA[64 * 68];    // [row][k]
  __shared__ _Float16 sW[128 * 68];   // [col][k] (transposed)
  int t = threadIdx.x;
  int n0 = blockIdx.x * 64;

  for (int f = t; f < 1024; f += 256) {
    int r = f >> 4, c4 = f & 15;
    int n = n0 + r;
    float4 v = {0.0f, 0.0f, 0.0f, 0.0f};
    if (n < N_NODES) v = *(const float4*)&x[(size_t)n * 64 + c4 * 4];
    union { _Float16 h[4]; float2 f2; } u;
    u.h[0] = (_Float16)v.x; u.h[1] = (_Float16)v.y;
    u.h[2] = (_Float16)v.z; u.h[3] = (_Float16)v.w;
    *(float2*)&sA[r * 68 + c4 * 4] = u.f2;
  }
  for (int f = t; f < 2048; f += 256) {
    int k = f >> 5, c4 = f & 31;
    float4 w = (c4 < 16) ? *(const float4*)&Wl[k * 64 + c4 * 4]
                         : *(const float4*)&Wr[k * 64 + (c4 - 16) * 4];
    int c = c4 * 4;
    sW[(c + 0) * 68 + k] = (_Float16)w.x;
    sW[(c + 1) * 68 + k] = (_Float16)w.y;
    sW[(c + 2) * 68 + k] = (_Float16)w.z;
    sW[(c + 3) * 68 + k] = (_Float16)w.w;
  }
  __syncthreads();

  int w = t >> 6, lane = t & 63;
  int m = lane & 31, half = lane >> 5;
  int rt = w & 1, cg = w >> 1;

  f32x16 acc[2];
#pragma unroll
  for (int r = 0; r < 16; ++r) { acc[0][r] = 0.0f; acc[1][r] = 0.0f; }

  const _Float16* pA = &sA[(rt * 32 + m) * 68 + half * 8];
  const _Float16* pB0 = &sW[(cg * 64 + m) * 68 + half * 8];
  const _Float16* pB1 = &sW[(cg * 64 + 32 + m) * 68 + half * 8];
#pragma unroll
  for (int kc = 0; kc < 4; ++kc) {
    union { f16x8 v; float2 f2[2]; } a, b0, b1;
    a.f2[0] = *(const float2*)(pA + kc * 16);
    a.f2[1] = *(const float2*)(pA + kc * 16 + 4);
    b0.f2[0] = *(const float2*)(pB0 + kc * 16);
    b0.f2[1] = *(const float2*)(pB0 + kc * 16 + 4);
    b1.f2[0] = *(const float2*)(pB1 + kc * 16);
    b1.f2[1] = *(const float2*)(pB1 + kc * 16 + 4);
    acc[0] = __builtin_amdgcn_mfma_f32_32x32x16_f16(a.v, b0.v, acc[0], 0, 0, 0);
    acc[1] = __builtin_amdgcn_mfma_f32_32x32x16_f16(a.v, b1.v, acc[1], 0, 0, 0);
  }

  if (cg == 0) {
#pragma unroll
    for (int tt = 0; tt < 2; ++tt) {
      int col = tt * 32 + m;
#pragma unroll
      for (int r = 0; r < 16; ++r) {
        int row = (r & 3) + 4 * half + 8 * (r >> 2);
        int n = n0 + rt * 32 + row;
        if (n < N_NODES) p[(size_t)n * 64 + col] = __float2half(acc[tt][r]);
      }
    }
  } else {
    float bias[2] = {b[m], b[32 + m]};
#pragma unroll
    for (int tt = 0; tt < 2; ++tt) {
      int col = tt * 32 + m;
#pragma unroll
      for (int r = 0; r < 16; ++r) {
        int row = (r & 3) + 4 * half + 8 * (r >> 2);
        int n = n0 + rt * 32 + row;
        if (n < N_NODES)
          q[(size_t)n * 64 + col] = __float2half(acc[tt][r] + bias[tt]);
      }
    }
  }
}

// ---------------------------------------------------------------------------
// Fuse 1: h[n] = relu(mean_j p1[csr_j] + q1[n]) in place over q1 (fp16).
// float4 gathers, 8 lanes/node, 8-deep unroll for MLP.
// ---------------------------------------------------------------------------
__global__ __launch_bounds__(256) void k_fuse1(
    const float4* __restrict__ p1, const int* __restrict__ rowstart,
    const int* __restrict__ cnt, const int* __restrict__ csr,
    float4* __restrict__ q1h) {
  int t = threadIdx.x;
  int n = blockIdx.x * 32 + (t >> 3);  // 3125*32 = 100000 exact
  int c4 = t & 7;
  int row = rowstart[n];
  int deg = cnt[n];
  float acc[8];
#pragma unroll
  for (int m = 0; m < 8; ++m) acc[m] = 0.0f;
  int j = 0;
  for (; j + 8 <= deg; j += 8) {
    int idx[8];
#pragma unroll
    for (int u = 0; u < 8; ++u) idx[u] = csr[row + j + u];
    float4 av[8];
#pragma unroll
    for (int u = 0; u < 8; ++u) av[u] = p1[idx[u] * 8 + c4];
#pragma unroll
    for (int u = 0; u < 8; ++u) {
      const __half2* h = (const __half2*)&av[u];
#pragma unroll
      for (int m = 0; m < 4; ++m) {
        float2 f = __half22float2(h[m]);
        acc[2 * m] += f.x;
        acc[2 * m + 1] += f.y;
      }
    }
  }
  for (; j + 4 <= deg; j += 4) {
    int idx[4];
#pragma unroll
    for (int u = 0; u < 4; ++u) idx[u] = csr[row + j + u];
    float4 av[4];
#pragma unroll
    for (int u = 0; u < 4; ++u) av[u] = p1[idx[u] * 8 + c4];
#pragma unroll
    for (int u = 0; u < 4; ++u) {
      const __half2* h = (const __half2*)&av[u];
#pragma unroll
      for (int m = 0; m < 4; ++m) {
        float2 f = __half22float2(h[m]);
        acc[2 * m] += f.x;
        acc[2 * m + 1] += f.y;
      }
    }
  }
  for (; j < deg; ++j) {
    float4 a = p1[csr[row + j] * 8 + c4];
    const __half2* h = (const __half2*)&a;
#pragma unroll
    for (int m = 0; m < 4; ++m) {
      float2 f = __half22float2(h[m]);
      acc[2 * m] += f.x;
      acc[2 * m + 1] += f.y;
    }
  }
  float inv = 1.0f / fmaxf((float)deg, 1.0f);
  int o = n * 8 + c4;
  float4 qv = q1h[o];
  __half2* qh = (__half2*)&qv;
  float4 r;
  __half2* rh = (__half2*)&r;
#pragma unroll
  for (int m = 0; m < 4; ++m) {
    float2 f = __half22float2(qh[m]);
    float2 s;
    s.x = fmaxf(acc[2 * m] * inv + f.x, 0.0f);
    s.y = fmaxf(acc[2 * m + 1] * inv + f.y, 0.0f);
    rh[m] = __float22half2_rn(s);
  }
  q1h[o] = r;
}

// ---------------------------------------------------------------------------
// GEMM 2 (MFMA): p2(fp16) = h @ W2l ; q2(fp32) = h @ W2r + b2
// ---------------------------------------------------------------------------
__global__ __launch_bounds__(256) void k_gemm2(
    const __half* __restrict__ h, const float* __restrict__ Wl,
    const float* __restrict__ Wr, const float* __restrict__ b,
    __half* __restrict__ p, float* __restrict__ q) {
  __shared__ _Float16 sA[128 * 68];
  __shared__ _Float16 sW[32 * 68];
  int t = threadIdx.x;
  int n0 = blockIdx.x * 128;

  for (int f = t; f < 2048; f += 256) {
    int r = f >> 4, c4 = f & 15;
    int n = n0 + r;
    float2 v = {0.0f, 0.0f};
    if (n < N_NODES) v = *(const float2*)&h[(size_t)n * 64 + c4 * 4];
    *(float2*)&sA[r * 68 + c4 * 4] = v;
  }
  for (int f = t; f < 512; f += 256) {
    int k = f >> 3, c4 = f & 7;
    float4 w = (c4 < 4) ? *(const float4*)&Wl[k * 16 + c4 * 4]
                        : *(const float4*)&Wr[k * 16 + (c4 - 4) * 4];
    int c = c4 * 4;
    sW[(c + 0) * 68 + k] = (_Float16)w.x;
    sW[(c + 1) * 68 + k] = (_Float16)w.y;
    sW[(c + 2) * 68 + k] = (_Float16)w.z;
    sW[(c + 3) * 68 + k] = (_Float16)w.w;
  }
  __syncthreads();

  int w = t >> 6, lane = t & 63;
  int m = lane & 31, half = lane >> 5;

  f32x16 acc;
#pragma unroll
  for (int r = 0; r < 16; ++r) acc[r] = 0.0f;

  const _Float16* pA = &sA[(w * 32 + m) * 68 + half * 8];
  const _Float16* pB = &sW[m * 68 + half * 8];
#pragma unroll
  for (int kc = 0; kc < 4; ++kc) {
    union { f16x8 v; float2 f2[2]; } a, bb;
    a.f2[0] = *(const float2*)(pA + kc * 16);
    a.f2[1] = *(const float2*)(pA + kc * 16 + 4);
    bb.f2[0] = *(const float2*)(pB + kc * 16);
    bb.f2[1] = *(const float2*)(pB + kc * 16 + 4);
    acc = __builtin_amdgcn_mfma_f32_32x32x16_f16(a.v, bb.v, acc, 0, 0, 0);
  }

  if (m < 16) {
#pragma unroll
    for (int r = 0; r < 16; ++r) {
      int row = (r & 3) + 4 * half + 8 * (r >> 2);
      int n = n0 + w * 32 + row;
      if (n < N_NODES) p[(size_t)n * 16 + m] = __float2half(acc[r]);
    }
  } else {
    float bias = b[m - 16];
#pragma unroll
    for (int r = 0; r < 16; ++r) {
      int row = (r & 3) + 4 * half + 8 * (r >> 2);
      int n = n0 + w * 32 + row;
      if (n < N_NODES) q[(size_t)n * 16 + (m - 16)] = acc[r] + bias;
    }
  }
}

// ---------------------------------------------------------------------------
// Fuse 2: out[n] = mean_j p2[csr_j] + q2[n].
// float4 gathers, 2 lanes/node, 8-deep unroll.
// ---------------------------------------------------------------------------
__global__ __launch_bounds__(256) void k_fuse2(
    const float4* __restrict__ p2, const float4* __restrict__ q2,
    const int* __restrict__ rowstart, const int* __restrict__ cnt,
    const int* __restrict__ csr, float4* __restrict__ out) {
  int t = threadIdx.x;
  int n = blockIdx.x * 128 + (t >> 1);
  if (n >= N_NODES) return;
  int c8 = t & 1;
  int row = rowstart[n];
  int deg = cnt[n];
  float acc[8];
#pragma unroll
  for (int m = 0; m < 8; ++m) acc[m] = 0.0f;
  int j = 0;
  for (; j + 8 <= deg; j += 8) {
    int idx[8];
#pragma unroll
    for (int u = 0; u < 8; ++u) idx[u] = csr[row + j + u];
    float4 av[8];
#pragma unroll
    for (int u = 0; u < 8; ++u) av[u] = p2[idx[u] * 2 + c8];
#pragma unroll
    for (int u = 0; u < 8; ++u) {
      const __half2* h = (const __half2*)&av[u];
#pragma unroll
      for (int m = 0; m < 4; ++m) {
        float2 f = __half22float2(h[m]);
        acc[2 * m] += f.x;
        acc[2 * m + 1] += f.y;
      }
    }
  }
  for (; j < deg; ++j) {
    float4 a = p2[csr[row + j] * 2 + c8];
    const __half2* h = (const __half2*)&a;
#pragma unroll
    for (int m = 0; m < 4; ++m) {
      float2 f = __half22float2(h[m]);
      acc[2 * m] += f.x;
      acc[2 * m + 1] += f.y;
    }
  }
  float inv = 1.0f / fmaxf((float)deg, 1.0f);
  float4 q0 = q2[n * 4 + c8 * 2];
  float4 q1v = q2[n * 4 + c8 * 2 + 1];
  float4 o0 = {acc[0] * inv + q0.x, acc[1] * inv + q0.y,
               acc[2] * inv + q0.z, acc[3] * inv + q0.w};
  float4 o1 = {acc[4] * inv + q1v.x, acc[5] * inv + q1v.y,
               acc[6] * inv + q1v.z, acc[7] * inv + q1v.w};
  out[n * 4 + c8 * 2] = o0;
  out[n * 4 + c8 * 2 + 1] = o1;
}

extern "C" void kernel_launch(void* const* d_in, const int* in_sizes, int n_in,
                              void* d_out, int out_size, void* d_ws, size_t ws_size,
                              hipStream_t stream) {
  const float* x   = (const float*)d_in[0];
  const int* edge  = (const int*)d_in[1];
  const int* src   = edge;            // edge_index[0]
  const int* dst   = edge + N_EDGES;  // edge_index[1]
  const float* W1l = (const float*)d_in[2];
  const float* b1  = (const float*)d_in[3];
  const float* W1r = (const float*)d_in[4];
  const float* W2l = (const float*)d_in[5];
  const float* b2  = (const float*)d_in[6];
  const float* W2r = (const float*)d_in[7];
  float* out = (float*)d_out;

  // workspace layout (4-byte units; p1 base is 16B aligned)
  int* S        = (int*)d_ws;          // LM = 200192 (bucket count matrix)
  int* bsum     = S + LM;              // 1024
  int* R        = bsum + 1024;         // LM (scanned bucket offsets)
  int* rowstart = R + LM;              // 100000
  int* cnt      = rowstart + N_NODES;  // 100000
  int* binned   = cnt + N_NODES;       // 1600000
  int* csr      = binned + N_EDGES;    // 1600000
  __half* p1    = (__half*)(csr + N_EDGES);    // 6.4M halves (12.8 MB)
  __half* q1h   = p1 + (size_t)N_NODES * 64;   // 6.4M halves (q1 -> h in place)
  __half* p2    = p1;                          // layer-2 reuse (p1 dead)
  float* q2     = (float*)(p1 + (size_t)N_NODES * 16);  // after p2 (3.2MB)

  // --- CSR build: 6 dispatches, no global atomics ---
  k_count<<<GB, 512, 0, stream>>>(dst, S);
  gscan_a<<<NBM, 256, 0, stream>>>(S, bsum, LM);
  gscan_b<<<1, 1024, 0, stream>>>(bsum, NBM);
  gscan_c<<<NBM, 256, 0, stream>>>(S, bsum, R, LM);
  k_binscatter<<<GB, 512, 0, stream>>>(src, dst, R, binned);
  k_finalize<<<NBKT, 512, 0, stream>>>(binned, R, csr, rowstart, cnt);

  // --- layer 1 ---
  k_gemm1<<<(N_NODES + 63) / 64, 256, 0, stream>>>(x, W1l, W1r, b1, p1, q1h);
  k_fuse1<<<N_NODES / 32, 256, 0, stream>>>((const float4*)p1, rowstart, cnt,
                                            csr, (float4*)q1h);

  // --- layer 2 ---
  k_gemm2<<<(N_NODES + 127) / 128, 256, 0, stream>>>(q1h, W2l, W2r, b2, p2, q2);
  k_fuse2<<<(N_NODES + 127) / 128, 256, 0, stream>>>((const float4*)p2,
                                                     (const float4*)q2,
                                                     rowstart, cnt, csr,
                                                     (float4*)out);
}

// Round 11
// 202.452 us; speedup vs baseline: 1.2061x; 1.0058x over previous
//
#include <hip/hip_runtime.h>
#include <hip/hip_fp16.h>

#define N_NODES 100000
#define N_EDGES 1600000
#define IN_C 64
#define HID_C 64
#define OUT_C 16

#define BKT 256        // nodes per dst bucket
#define BSH 8          // dst >> 8 = bucket
#define NBKT 391       // ceil(100000/256)
#define CAP 5120       // slots per bucket (mean 4092, +16 sigma margin)
#define GB 512         // blocks in edge-binning pass
#define EPB 3125       // edges per binning block (512*3125 = 1.6M exact)

typedef _Float16 f16x8 __attribute__((ext_vector_type(8)));
typedef float f32x16 __attribute__((ext_vector_type(16)));

// ---------------------------------------------------------------------------
// k_bin (fused count+scatter): per-block LDS bucket histogram -> one global
// atomicAdd per (block,bucket) reserves a range inside the bucket's fixed
// CAP region -> scatter edges. No scan, no global compactness needed.
// Entry packs (src<<8)|dst_local.
// ---------------------------------------------------------------------------
__global__ __launch_bounds__(512) void k_bin(
    const int* __restrict__ src, const int* __restrict__ dst,
    int* __restrict__ gcnt, int* __restrict__ binned) {
  __shared__ int h[NBKT];
  __shared__ int cur[NBKT];
  int t = threadIdx.x;
  for (int i = t; i < NBKT; i += 512) h[i] = 0;
  __syncthreads();
  int base = blockIdx.x * EPB;
  int end = base + EPB;
  for (int e = base + t; e < end; e += 512)
    atomicAdd(&h[dst[e] >> BSH], 1);
  __syncthreads();
  for (int i = t; i < NBKT; i += 512) {
    int c = h[i];
    int b0 = atomicAdd(&gcnt[i], c);   // reserve [b0, b0+c) in bucket i
    cur[i] = i * CAP + b0;
  }
  __syncthreads();
  for (int e = base + t; e < end; e += 512) {  // dst slice is L1-hot now
    int d = dst[e];
    int pos = atomicAdd(&cur[d >> BSH], 1);
    binned[pos] = (src[e] << BSH) | (d & (BKT - 1));
  }
}

// ---------------------------------------------------------------------------
// k_finalize: per-bucket node histogram -> LDS exclusive scan -> rowstart/cnt
// -> scatter binned segment to (bucket-padded) CSR. No global atomics.
// ---------------------------------------------------------------------------
__global__ __launch_bounds__(512) void k_finalize(
    const int* __restrict__ binned, const int* __restrict__ gcnt,
    int* __restrict__ csr, int* __restrict__ rowstart, int* __restrict__ cnt) {
  int b = blockIdx.x;
  __shared__ int hcnt[BKT];
  __shared__ int hscan[BKT];
  __shared__ int cur[BKT];
  int t = threadIdx.x;
  if (t < BKT) hcnt[t] = 0;
  __syncthreads();
  int start = b * CAP;
  int end = start + gcnt[b];
  for (int i = start + t; i < end; i += 512)
    atomicAdd(&hcnt[binned[i] & (BKT - 1)], 1);
  __syncthreads();
  int v = 0;
  if (t < BKT) {
    v = hcnt[t];
    hscan[t] = v;
  }
  __syncthreads();
  for (int st = 1; st < 256; st <<= 1) {
    int a = 0;
    if (t < BKT && t >= st) a = hscan[t - st];
    __syncthreads();
    if (t < BKT) hscan[t] += a;
    __syncthreads();
  }
  if (t < BKT) {
    int rs = start + hscan[t] - v;  // rowstart of node b*BKT + t
    cur[t] = rs;
    int n = (b << BSH) + t;
    if (n < N_NODES) {
      rowstart[n] = rs;
      cnt[n] = v;
    }
  }
  __syncthreads();
  for (int i = start + t; i < end; i += 512) {
    int vv = binned[i];
    int pos = atomicAdd(&cur[vv & (BKT - 1)], 1);
    csr[pos] = vv >> BSH;
  }
}

// ---------------------------------------------------------------------------
// GEMM 1 (MFMA): p(fp16) = x @ Wl ; q(fp16) = x @ Wr + b
// Block = 64 rows x 128 cols, 4 waves, 32x32x16 f16 MFMA.
// ---------------------------------------------------------------------------
__global__ __launch_bounds__(256) void k_gemm1(
    const float* __restrict__ x, const float* __restrict__ Wl,
    const float* __restrict__ Wr, const float* __restrict__ b,
    __half* __restrict__ p, __half* __restrict__ q) {
  __shared__ _Float16 sA[64 * 68];    // [row][k]
  __shared__ _Float16 sW[128 * 68];   // [col][k] (transposed)
  int t = threadIdx.x;
  int n0 = blockIdx.x * 64;

  for (int f = t; f < 1024; f += 256) {
    int r = f >> 4, c4 = f & 15;
    int n = n0 + r;
    float4 v = {0.0f, 0.0f, 0.0f, 0.0f};
    if (n < N_NODES) v = *(const float4*)&x[(size_t)n * 64 + c4 * 4];
    union { _Float16 h[4]; float2 f2; } u;
    u.h[0] = (_Float16)v.x; u.h[1] = (_Float16)v.y;
    u.h[2] = (_Float16)v.z; u.h[3] = (_Float16)v.w;
    *(float2*)&sA[r * 68 + c4 * 4] = u.f2;
  }
  for (int f = t; f < 2048; f += 256) {
    int k = f >> 5, c4 = f & 31;
    float4 w = (c4 < 16) ? *(const float4*)&Wl[k * 64 + c4 * 4]
                         : *(const float4*)&Wr[k * 64 + (c4 - 16) * 4];
    int c = c4 * 4;
    sW[(c + 0) * 68 + k] = (_Float16)w.x;
    sW[(c + 1) * 68 + k] = (_Float16)w.y;
    sW[(c + 2) * 68 + k] = (_Float16)w.z;
    sW[(c + 3) * 68 + k] = (_Float16)w.w;
  }
  __syncthreads();

  int w = t >> 6, lane = t & 63;
  int m = lane & 31, half = lane >> 5;
  int rt = w & 1, cg = w >> 1;

  f32x16 acc[2];
#pragma unroll
  for (int r = 0; r < 16; ++r) { acc[0][r] = 0.0f; acc[1][r] = 0.0f; }

  const _Float16* pA = &sA[(rt * 32 + m) * 68 + half * 8];
  const _Float16* pB0 = &sW[(cg * 64 + m) * 68 + half * 8];
  const _Float16* pB1 = &sW[(cg * 64 + 32 + m) * 68 + half * 8];
#pragma unroll
  for (int kc = 0; kc < 4; ++kc) {
    union { f16x8 v; float2 f2[2]; } a, b0, b1;
    a.f2[0] = *(const float2*)(pA + kc * 16);
    a.f2[1] = *(const float2*)(pA + kc * 16 + 4);
    b0.f2[0] = *(const float2*)(pB0 + kc * 16);
    b0.f2[1] = *(const float2*)(pB0 + kc * 16 + 4);
    b1.f2[0] = *(const float2*)(pB1 + kc * 16);
    b1.f2[1] = *(const float2*)(pB1 + kc * 16 + 4);
    acc[0] = __builtin_amdgcn_mfma_f32_32x32x16_f16(a.v, b0.v, acc[0], 0, 0, 0);
    acc[1] = __builtin_amdgcn_mfma_f32_32x32x16_f16(a.v, b1.v, acc[1], 0, 0, 0);
  }

  if (cg == 0) {
#pragma unroll
    for (int tt = 0; tt < 2; ++tt) {
      int col = tt * 32 + m;
#pragma unroll
      for (int r = 0; r < 16; ++r) {
        int row = (r & 3) + 4 * half + 8 * (r >> 2);
        int n = n0 + rt * 32 + row;
        if (n < N_NODES) p[(size_t)n * 64 + col] = __float2half(acc[tt][r]);
      }
    }
  } else {
    float bias[2] = {b[m], b[32 + m]};
#pragma unroll
    for (int tt = 0; tt < 2; ++tt) {
      int col = tt * 32 + m;
#pragma unroll
      for (int r = 0; r < 16; ++r) {
        int row = (r & 3) + 4 * half + 8 * (r >> 2);
        int n = n0 + rt * 32 + row;
        if (n < N_NODES)
          q[(size_t)n * 64 + col] = __float2half(acc[tt][r] + bias[tt]);
      }
    }
  }
}

// ---------------------------------------------------------------------------
// Fuse 1: h[n] = relu(mean_j p1[csr_j] + q1[n]) in place over q1 (fp16).
// float4 gathers, 8 lanes/node, 8-deep unroll for MLP.
// ---------------------------------------------------------------------------
__global__ __launch_bounds__(256) void k_fuse1(
    const float4* __restrict__ p1, const int* __restrict__ rowstart,
    const int* __restrict__ cnt, const int* __restrict__ csr,
    float4* __restrict__ q1h) {
  int t = threadIdx.x;
  int n = blockIdx.x * 32 + (t >> 3);  // 3125*32 = 100000 exact
  int c4 = t & 7;
  int row = rowstart[n];
  int deg = cnt[n];
  float acc[8];
#pragma unroll
  for (int m = 0; m < 8; ++m) acc[m] = 0.0f;
  int j = 0;
  for (; j + 8 <= deg; j += 8) {
    int idx[8];
#pragma unroll
    for (int u = 0; u < 8; ++u) idx[u] = csr[row + j + u];
    float4 av[8];
#pragma unroll
    for (int u = 0; u < 8; ++u) av[u] = p1[idx[u] * 8 + c4];
#pragma unroll
    for (int u = 0; u < 8; ++u) {
      const __half2* h = (const __half2*)&av[u];
#pragma unroll
      for (int m = 0; m < 4; ++m) {
        float2 f = __half22float2(h[m]);
        acc[2 * m] += f.x;
        acc[2 * m + 1] += f.y;
      }
    }
  }
  for (; j + 4 <= deg; j += 4) {
    int idx[4];
#pragma unroll
    for (int u = 0; u < 4; ++u) idx[u] = csr[row + j + u];
    float4 av[4];
#pragma unroll
    for (int u = 0; u < 4; ++u) av[u] = p1[idx[u] * 8 + c4];
#pragma unroll
    for (int u = 0; u < 4; ++u) {
      const __half2* h = (const __half2*)&av[u];
#pragma unroll
      for (int m = 0; m < 4; ++m) {
        float2 f = __half22float2(h[m]);
        acc[2 * m] += f.x;
        acc[2 * m + 1] += f.y;
      }
    }
  }
  for (; j < deg; ++j) {
    float4 a = p1[csr[row + j] * 8 + c4];
    const __half2* h = (const __half2*)&a;
#pragma unroll
    for (int m = 0; m < 4; ++m) {
      float2 f = __half22float2(h[m]);
      acc[2 * m] += f.x;
      acc[2 * m + 1] += f.y;
    }
  }
  float inv = 1.0f / fmaxf((float)deg, 1.0f);
  int o = n * 8 + c4;
  float4 qv = q1h[o];
  __half2* qh = (__half2*)&qv;
  float4 r;
  __half2* rh = (__half2*)&r;
#pragma unroll
  for (int m = 0; m < 4; ++m) {
    float2 f = __half22float2(qh[m]);
    float2 s;
    s.x = fmaxf(acc[2 * m] * inv + f.x, 0.0f);
    s.y = fmaxf(acc[2 * m + 1] * inv + f.y, 0.0f);
    rh[m] = __float22half2_rn(s);
  }
  q1h[o] = r;
}

// ---------------------------------------------------------------------------
// GEMM 2 (MFMA): p2(fp16) = h @ W2l ; q2(fp32) = h @ W2r + b2
// ---------------------------------------------------------------------------
__global__ __launch_bounds__(256) void k_gemm2(
    const __half* __restrict__ h, const float* __restrict__ Wl,
    const float* __restrict__ Wr, const float* __restrict__ b,
    __half* __restrict__ p, float* __restrict__ q) {
  __shared__ _Float16 sA[128 * 68];
  __shared__ _Float16 sW[32 * 68];
  int t = threadIdx.x;
  int n0 = blockIdx.x * 128;

  for (int f = t; f < 2048; f += 256) {
    int r = f >> 4, c4 = f & 15;
    int n = n0 + r;
    float2 v = {0.0f, 0.0f};
    if (n < N_NODES) v = *(const float2*)&h[(size_t)n * 64 + c4 * 4];
    *(float2*)&sA[r * 68 + c4 * 4] = v;
  }
  for (int f = t; f < 512; f += 256) {
    int k = f >> 3, c4 = f & 7;
    float4 w = (c4 < 4) ? *(const float4*)&Wl[k * 16 + c4 * 4]
                        : *(const float4*)&Wr[k * 16 + (c4 - 4) * 4];
    int c = c4 * 4;
    sW[(c + 0) * 68 + k] = (_Float16)w.x;
    sW[(c + 1) * 68 + k] = (_Float16)w.y;
    sW[(c + 2) * 68 + k] = (_Float16)w.z;
    sW[(c + 3) * 68 + k] = (_Float16)w.w;
  }
  __syncthreads();

  int w = t >> 6, lane = t & 63;
  int m = lane & 31, half = lane >> 5;

  f32x16 acc;
#pragma unroll
  for (int r = 0; r < 16; ++r) acc[r] = 0.0f;

  const _Float16* pA = &sA[(w * 32 + m) * 68 + half * 8];
  const _Float16* pB = &sW[m * 68 + half * 8];
#pragma unroll
  for (int kc = 0; kc < 4; ++kc) {
    union { f16x8 v; float2 f2[2]; } a, bb;
    a.f2[0] = *(const float2*)(pA + kc * 16);
    a.f2[1] = *(const float2*)(pA + kc * 16 + 4);
    bb.f2[0] = *(const float2*)(pB + kc * 16);
    bb.f2[1] = *(const float2*)(pB + kc * 16 + 4);
    acc = __builtin_amdgcn_mfma_f32_32x32x16_f16(a.v, bb.v, acc, 0, 0, 0);
  }

  if (m < 16) {
#pragma unroll
    for (int r = 0; r < 16; ++r) {
      int row = (r & 3) + 4 * half + 8 * (r >> 2);
      int n = n0 + w * 32 + row;
      if (n < N_NODES) p[(size_t)n * 16 + m] = __float2half(acc[r]);
    }
  } else {
    float bias = b[m - 16];
#pragma unroll
    for (int r = 0; r < 16; ++r) {
      int row = (r & 3) + 4 * half + 8 * (r >> 2);
      int n = n0 + w * 32 + row;
      if (n < N_NODES) q[(size_t)n * 16 + (m - 16)] = acc[r] + bias;
    }
  }
}

// ---------------------------------------------------------------------------
// Fuse 2: out[n] = mean_j p2[csr_j] + q2[n].
// float4 gathers, 2 lanes/node, 8-deep unroll.
// ---------------------------------------------------------------------------
__global__ __launch_bounds__(256) void k_fuse2(
    const float4* __restrict__ p2, const float4* __restrict__ q2,
    const int* __restrict__ rowstart, const int* __restrict__ cnt,
    const int* __restrict__ csr, float4* __restrict__ out) {
  int t = threadIdx.x;
  int n = blockIdx.x * 128 + (t >> 1);
  if (n >= N_NODES) return;
  int c8 = t & 1;
  int row = rowstart[n];
  int deg = cnt[n];
  float acc[8];
#pragma unroll
  for (int m = 0; m < 8; ++m) acc[m] = 0.0f;
  int j = 0;
  for (; j + 8 <= deg; j += 8) {
    int idx[8];
#pragma unroll
    for (int u = 0; u < 8; ++u) idx[u] = csr[row + j + u];
    float4 av[8];
#pragma unroll
    for (int u = 0; u < 8; ++u) av[u] = p2[idx[u] * 2 + c8];
#pragma unroll
    for (int u = 0; u < 8; ++u) {
      const __half2* h = (const __half2*)&av[u];
#pragma unroll
      for (int m = 0; m < 4; ++m) {
        float2 f = __half22float2(h[m]);
        acc[2 * m] += f.x;
        acc[2 * m + 1] += f.y;
      }
    }
  }
  for (; j < deg; ++j) {
    float4 a = p2[csr[row + j] * 2 + c8];
    const __half2* h = (const __half2*)&a;
#pragma unroll
    for (int m = 0; m < 4; ++m) {
      float2 f = __half22float2(h[m]);
      acc[2 * m] += f.x;
      acc[2 * m + 1] += f.y;
    }
  }
  float inv = 1.0f / fmaxf((float)deg, 1.0f);
  float4 q0 = q2[n * 4 + c8 * 2];
  float4 q1v = q2[n * 4 + c8 * 2 + 1];
  float4 o0 = {acc[0] * inv + q0.x, acc[1] * inv + q0.y,
               acc[2] * inv + q0.z, acc[3] * inv + q0.w};
  float4 o1 = {acc[4] * inv + q1v.x, acc[5] * inv + q1v.y,
               acc[6] * inv + q1v.z, acc[7] * inv + q1v.w};
  out[n * 4 + c8 * 2] = o0;
  out[n * 4 + c8 * 2 + 1] = o1;
}

extern "C" void kernel_launch(void* const* d_in, const int* in_sizes, int n_in,
                              void* d_out, int out_size, void* d_ws, size_t ws_size,
                              hipStream_t stream) {
  const float* x   = (const float*)d_in[0];
  const int* edge  = (const int*)d_in[1];
  const int* src   = edge;            // edge_index[0]
  const int* dst   = edge + N_EDGES;  // edge_index[1]
  const float* W1l = (const float*)d_in[2];
  const float* b1  = (const float*)d_in[3];
  const float* W1r = (const float*)d_in[4];
  const float* W2l = (const float*)d_in[5];
  const float* b2  = (const float*)d_in[6];
  const float* W2r = (const float*)d_in[7];
  float* out = (float*)d_out;

  // workspace layout (4-byte units; p1 base is 16B aligned)
  int* gcnt     = (int*)d_ws;          // 391 (padded to 512)
  int* rowstart = gcnt + 512;          // 100000
  int* cnt      = rowstart + N_NODES;  // 100000
  int* binned   = cnt + N_NODES;       // NBKT*CAP = 2001920
  int* csr      = binned + NBKT * CAP; // 2001920
  __half* p1    = (__half*)(csr + NBKT * CAP);  // 6.4M halves (12.8 MB)
  __half* q1h   = p1 + (size_t)N_NODES * 64;    // 6.4M halves (q1 -> h in place)
  __half* p2    = p1;                           // layer-2 reuse (p1 dead)
  float* q2     = (float*)(p1 + (size_t)N_NODES * 16);  // after p2 (3.2MB)

  hipMemsetAsync(gcnt, 0, NBKT * sizeof(int), stream);

  // --- CSR build: 2 dispatches, bucket-padded layout ---
  k_bin<<<GB, 512, 0, stream>>>(src, dst, gcnt, binned);
  k_finalize<<<NBKT, 512, 0, stream>>>(binned, gcnt, csr, rowstart, cnt);

  // --- layer 1 ---
  k_gemm1<<<(N_NODES + 63) / 64, 256, 0, stream>>>(x, W1l, W1r, b1, p1, q1h);
  k_fuse1<<<N_NODES / 32, 256, 0, stream>>>((const float4*)p1, rowstart, cnt,
                                            csr, (float4*)q1h);

  // --- layer 2 ---
  k_gemm2<<<(N_NODES + 127) / 128, 256, 0, stream>>>(q1h, W2l, W2r, b2, p2, q2);
  k_fuse2<<<(N_NODES + 127) / 128, 256, 0, stream>>>((const float4*)p2,
                                                     (const float4*)q2,
                                                     rowstart, cnt, csr,
                                                     (float4*)out);
}

// Round 12
// 193.039 us; speedup vs baseline: 1.2649x; 1.0488x over previous
//
#include <hip/hip_runtime.h>
#include <hip/hip_fp16.h>

#define N_NODES 100000
#define N_EDGES 1600000
#define IN_C 64
#define HID_C 64
#define OUT_C 16

#define BKT 256        // nodes per dst bucket
#define BSH 8          // dst >> 8 = bucket
#define NBKT 391       // ceil(100000/256)
#define CAP 5120       // slots per bucket (mean 4092, +16 sigma margin)
#define GB 512         // bin sub-blocks in merged pass 1
#define EPB 3125       // edges per bin block (512*3125 = 1.6M exact)
#define G1B 1563       // gemm1 sub-blocks = ceil(100000/64)

typedef _Float16 f16x8 __attribute__((ext_vector_type(8)));
typedef float f32x16 __attribute__((ext_vector_type(16)));

// ---------------------------------------------------------------------------
// Merged pass 1: blocks [0,GB) do edge binning; blocks [GB, GB+G1B) do GEMM1.
// Independent work overlapped in one dispatch (bin blocks first so they
// drain while gemm1 occupies the CUs).
// bin: per-block LDS bucket histogram -> one global atomicAdd per
// (block,bucket) reserves a range in the bucket's CAP region -> scatter.
// gemm1 (MFMA): p(fp16) = x @ W1l ; q(fp16) = x @ W1r + b1.
// ---------------------------------------------------------------------------
__global__ __launch_bounds__(256) void k_merged1(
    const int* __restrict__ src, const int* __restrict__ dst,
    int* __restrict__ gcnt, int* __restrict__ binned,
    const float* __restrict__ x, const float* __restrict__ Wl,
    const float* __restrict__ Wr, const float* __restrict__ b,
    __half* __restrict__ p, __half* __restrict__ q) {
  __shared__ _Float16 sA[64 * 68];    // gemm: [row][k]   | bin: h[] alias
  __shared__ _Float16 sW[128 * 68];   // gemm: [col][k]^T | bin: cur[] alias
  int t = threadIdx.x;

  if (blockIdx.x < GB) {
    // ---------------- bin body ----------------
    int* h   = (int*)sA;
    int* cur = (int*)sW;
    for (int i = t; i < NBKT; i += 256) h[i] = 0;
    __syncthreads();
    int base = blockIdx.x * EPB;
    int end = base + EPB;
    for (int e = base + t; e < end; e += 256)
      atomicAdd(&h[dst[e] >> BSH], 1);
    __syncthreads();
    for (int i = t; i < NBKT; i += 256) {
      int c = h[i];
      int b0 = atomicAdd(&gcnt[i], c);   // reserve [b0, b0+c) in bucket i
      cur[i] = i * CAP + b0;
    }
    __syncthreads();
    for (int e = base + t; e < end; e += 256) {  // dst slice L1-hot
      int d = dst[e];
      int pos = atomicAdd(&cur[d >> BSH], 1);
      binned[pos] = (src[e] << BSH) | (d & (BKT - 1));
    }
    return;
  }

  // ---------------- gemm1 body ----------------
  int n0 = (blockIdx.x - GB) * 64;

  for (int f = t; f < 1024; f += 256) {
    int r = f >> 4, c4 = f & 15;
    int n = n0 + r;
    float4 v = {0.0f, 0.0f, 0.0f, 0.0f};
    if (n < N_NODES) v = *(const float4*)&x[(size_t)n * 64 + c4 * 4];
    union { _Float16 h[4]; float2 f2; } u;
    u.h[0] = (_Float16)v.x; u.h[1] = (_Float16)v.y;
    u.h[2] = (_Float16)v.z; u.h[3] = (_Float16)v.w;
    *(float2*)&sA[r * 68 + c4 * 4] = u.f2;
  }
  for (int f = t; f < 2048; f += 256) {
    int k = f >> 5, c4 = f & 31;
    float4 w = (c4 < 16) ? *(const float4*)&Wl[k * 64 + c4 * 4]
                         : *(const float4*)&Wr[k * 64 + (c4 - 16) * 4];
    int c = c4 * 4;
    sW[(c + 0) * 68 + k] = (_Float16)w.x;
    sW[(c + 1) * 68 + k] = (_Float16)w.y;
    sW[(c + 2) * 68 + k] = (_Float16)w.z;
    sW[(c + 3) * 68 + k] = (_Float16)w.w;
  }
  __syncthreads();

  int w = t >> 6, lane = t & 63;
  int m = lane & 31, half = lane >> 5;
  int rt = w & 1, cg = w >> 1;

  f32x16 acc[2];
#pragma unroll
  for (int r = 0; r < 16; ++r) { acc[0][r] = 0.0f; acc[1][r] = 0.0f; }

  const _Float16* pA = &sA[(rt * 32 + m) * 68 + half * 8];
  const _Float16* pB0 = &sW[(cg * 64 + m) * 68 + half * 8];
  const _Float16* pB1 = &sW[(cg * 64 + 32 + m) * 68 + half * 8];
#pragma unroll
  for (int kc = 0; kc < 4; ++kc) {
    union { f16x8 v; float2 f2[2]; } a, b0, b1;
    a.f2[0] = *(const float2*)(pA + kc * 16);
    a.f2[1] = *(const float2*)(pA + kc * 16 + 4);
    b0.f2[0] = *(const float2*)(pB0 + kc * 16);
    b0.f2[1] = *(const float2*)(pB0 + kc * 16 + 4);
    b1.f2[0] = *(const float2*)(pB1 + kc * 16);
    b1.f2[1] = *(const float2*)(pB1 + kc * 16 + 4);
    acc[0] = __builtin_amdgcn_mfma_f32_32x32x16_f16(a.v, b0.v, acc[0], 0, 0, 0);
    acc[1] = __builtin_amdgcn_mfma_f32_32x32x16_f16(a.v, b1.v, acc[1], 0, 0, 0);
  }

  if (cg == 0) {
#pragma unroll
    for (int tt = 0; tt < 2; ++tt) {
      int col = tt * 32 + m;
#pragma unroll
      for (int r = 0; r < 16; ++r) {
        int row = (r & 3) + 4 * half + 8 * (r >> 2);
        int n = n0 + rt * 32 + row;
        if (n < N_NODES) p[(size_t)n * 64 + col] = __float2half(acc[tt][r]);
      }
    }
  } else {
    float bias[2] = {b[m], b[32 + m]};
#pragma unroll
    for (int tt = 0; tt < 2; ++tt) {
      int col = tt * 32 + m;
#pragma unroll
      for (int r = 0; r < 16; ++r) {
        int row = (r & 3) + 4 * half + 8 * (r >> 2);
        int n = n0 + rt * 32 + row;
        if (n < N_NODES)
          q[(size_t)n * 64 + col] = __float2half(acc[tt][r] + bias[tt]);
      }
    }
  }
}

// ---------------------------------------------------------------------------
// Fuse1b (finalize ∪ fuse1): one block per bucket (512 thr).
// Phase A: node histogram -> LDS scan -> scatter src indices into LDS lcsr;
//          write csr/rowstart/cnt to global as side product (for fuse2).
// Phase B: h[n] = relu(mean_j p1[lcsr_j] + q1[n]) in place over q1 (fp16).
//          64 groups of 8 lanes; each group owns 4 node slots.
// ---------------------------------------------------------------------------
__global__ __launch_bounds__(512) void k_fuse1b(
    const float4* __restrict__ p1, const int* __restrict__ gcnt,
    const int* __restrict__ binned, int* __restrict__ csr,
    int* __restrict__ rowstart, int* __restrict__ cnt,
    float4* __restrict__ q1h) {
  __shared__ int hcnt[BKT];
  __shared__ int hscan[BKT];
  __shared__ int cur[BKT];
  __shared__ int lcsr[CAP];
  int b = blockIdx.x;
  int t = threadIdx.x;
  if (t < BKT) hcnt[t] = 0;
  __syncthreads();
  int start = b * CAP;
  int total = gcnt[b];
  for (int i = t; i < total; i += 512)
    atomicAdd(&hcnt[binned[start + i] & (BKT - 1)], 1);
  __syncthreads();
  int v = 0;
  if (t < BKT) {
    v = hcnt[t];
    hscan[t] = v;
  }
  __syncthreads();
  for (int st = 1; st < 256; st <<= 1) {
    int a = 0;
    if (t < BKT && t >= st) a = hscan[t - st];
    __syncthreads();
    if (t < BKT) hscan[t] += a;
    __syncthreads();
  }
  if (t < BKT) {
    cur[t] = hscan[t] - v;          // local exclusive start
    int n = (b << BSH) + t;
    if (n < N_NODES) {
      rowstart[n] = start + hscan[t] - v;
      cnt[n] = v;
    }
  }
  __syncthreads();
  for (int i = t; i < total; i += 512) {
    int vv = binned[start + i];
    int pos = atomicAdd(&cur[vv & (BKT - 1)], 1);
    lcsr[pos] = vv >> BSH;
  }
  __syncthreads();
  // global csr for fuse2 (coalesced copy from LDS)
  for (int i = t; i < total; i += 512) csr[start + i] = lcsr[i];

  // ---- Phase B: aggregate ----
  int g = t >> 3, c4 = t & 7;
  for (int r = g; r < BKT; r += 64) {
    int n = (b << BSH) + r;
    if (n >= N_NODES) continue;
    int deg = hcnt[r];
    int row = hscan[r] - deg;  // local start in lcsr
    float acc[8];
#pragma unroll
    for (int m = 0; m < 8; ++m) acc[m] = 0.0f;
    int j = 0;
    for (; j + 8 <= deg; j += 8) {
      int idx[8];
#pragma unroll
      for (int u = 0; u < 8; ++u) idx[u] = lcsr[row + j + u];
      float4 av[8];
#pragma unroll
      for (int u = 0; u < 8; ++u) av[u] = p1[idx[u] * 8 + c4];
#pragma unroll
      for (int u = 0; u < 8; ++u) {
        const __half2* h = (const __half2*)&av[u];
#pragma unroll
        for (int m = 0; m < 4; ++m) {
          float2 f = __half22float2(h[m]);
          acc[2 * m] += f.x;
          acc[2 * m + 1] += f.y;
        }
      }
    }
    for (; j < deg; ++j) {
      float4 a = p1[lcsr[row + j] * 8 + c4];
      const __half2* h = (const __half2*)&a;
#pragma unroll
      for (int m = 0; m < 4; ++m) {
        float2 f = __half22float2(h[m]);
        acc[2 * m] += f.x;
        acc[2 * m + 1] += f.y;
      }
    }
    float inv = 1.0f / fmaxf((float)deg, 1.0f);
    int o = n * 8 + c4;
    float4 qv = q1h[o];
    __half2* qh = (__half2*)&qv;
    float4 res;
    __half2* rh = (__half2*)&res;
#pragma unroll
    for (int m = 0; m < 4; ++m) {
      float2 f = __half22float2(qh[m]);
      float2 s;
      s.x = fmaxf(acc[2 * m] * inv + f.x, 0.0f);
      s.y = fmaxf(acc[2 * m + 1] * inv + f.y, 0.0f);
      rh[m] = __float22half2_rn(s);
    }
    q1h[o] = res;
  }
}

// ---------------------------------------------------------------------------
// GEMM 2 (MFMA): p2(fp16) = h @ W2l ; q2(fp32) = h @ W2r + b2
// ---------------------------------------------------------------------------
__global__ __launch_bounds__(256) void k_gemm2(
    const __half* __restrict__ h, const float* __restrict__ Wl,
    const float* __restrict__ Wr, const float* __restrict__ b,
    __half* __restrict__ p, float* __restrict__ q) {
  __shared__ _Float16 sA[128 * 68];
  __shared__ _Float16 sW[32 * 68];
  int t = threadIdx.x;
  int n0 = blockIdx.x * 128;

  for (int f = t; f < 2048; f += 256) {
    int r = f >> 4, c4 = f & 15;
    int n = n0 + r;
    float2 v = {0.0f, 0.0f};
    if (n < N_NODES) v = *(const float2*)&h[(size_t)n * 64 + c4 * 4];
    *(float2*)&sA[r * 68 + c4 * 4] = v;
  }
  for (int f = t; f < 512; f += 256) {
    int k = f >> 3, c4 = f & 7;
    float4 w = (c4 < 4) ? *(const float4*)&Wl[k * 16 + c4 * 4]
                        : *(const float4*)&Wr[k * 16 + (c4 - 4) * 4];
    int c = c4 * 4;
    sW[(c + 0) * 68 + k] = (_Float16)w.x;
    sW[(c + 1) * 68 + k] = (_Float16)w.y;
    sW[(c + 2) * 68 + k] = (_Float16)w.z;
    sW[(c + 3) * 68 + k] = (_Float16)w.w;
  }
  __syncthreads();

  int w = t >> 6, lane = t & 63;
  int m = lane & 31, half = lane >> 5;

  f32x16 acc;
#pragma unroll
  for (int r = 0; r < 16; ++r) acc[r] = 0.0f;

  const _Float16* pA = &sA[(w * 32 + m) * 68 + half * 8];
  const _Float16* pB = &sW[m * 68 + half * 8];
#pragma unroll
  for (int kc = 0; kc < 4; ++kc) {
    union { f16x8 v; float2 f2[2]; } a, bb;
    a.f2[0] = *(const float2*)(pA + kc * 16);
    a.f2[1] = *(const float2*)(pA + kc * 16 + 4);
    bb.f2[0] = *(const float2*)(pB + kc * 16);
    bb.f2[1] = *(const float2*)(pB + kc * 16 + 4);
    acc = __builtin_amdgcn_mfma_f32_32x32x16_f16(a.v, bb.v, acc, 0, 0, 0);
  }

  if (m < 16) {
#pragma unroll
    for (int r = 0; r < 16; ++r) {
      int row = (r & 3) + 4 * half + 8 * (r >> 2);
      int n = n0 + w * 32 + row;
      if (n < N_NODES) p[(size_t)n * 16 + m] = __float2half(acc[r]);
    }
  } else {
    float bias = b[m - 16];
#pragma unroll
    for (int r = 0; r < 16; ++r) {
      int row = (r & 3) + 4 * half + 8 * (r >> 2);
      int n = n0 + w * 32 + row;
      if (n < N_NODES) q[(size_t)n * 16 + (m - 16)] = acc[r] + bias;
    }
  }
}

// ---------------------------------------------------------------------------
// Fuse 2: out[n] = mean_j p2[csr_j] + q2[n].
// float4 gathers, 2 lanes/node, 8-deep unroll.
// ---------------------------------------------------------------------------
__global__ __launch_bounds__(256) void k_fuse2(
    const float4* __restrict__ p2, const float4* __restrict__ q2,
    const int* __restrict__ rowstart, const int* __restrict__ cnt,
    const int* __restrict__ csr, float4* __restrict__ out) {
  int t = threadIdx.x;
  int n = blockIdx.x * 128 + (t >> 1);
  if (n >= N_NODES) return;
  int c8 = t & 1;
  int row = rowstart[n];
  int deg = cnt[n];
  float acc[8];
#pragma unroll
  for (int m = 0; m < 8; ++m) acc[m] = 0.0f;
  int j = 0;
  for (; j + 8 <= deg; j += 8) {
    int idx[8];
#pragma unroll
    for (int u = 0; u < 8; ++u) idx[u] = csr[row + j + u];
    float4 av[8];
#pragma unroll
    for (int u = 0; u < 8; ++u) av[u] = p2[idx[u] * 2 + c8];
#pragma unroll
    for (int u = 0; u < 8; ++u) {
      const __half2* h = (const __half2*)&av[u];
#pragma unroll
      for (int m = 0; m < 4; ++m) {
        float2 f = __half22float2(h[m]);
        acc[2 * m] += f.x;
        acc[2 * m + 1] += f.y;
      }
    }
  }
  for (; j < deg; ++j) {
    float4 a = p2[csr[row + j] * 2 + c8];
    const __half2* h = (const __half2*)&a;
#pragma unroll
    for (int m = 0; m < 4; ++m) {
      float2 f = __half22float2(h[m]);
      acc[2 * m] += f.x;
      acc[2 * m + 1] += f.y;
    }
  }
  float inv = 1.0f / fmaxf((float)deg, 1.0f);
  float4 q0 = q2[n * 4 + c8 * 2];
  float4 q1v = q2[n * 4 + c8 * 2 + 1];
  float4 o0 = {acc[0] * inv + q0.x, acc[1] * inv + q0.y,
               acc[2] * inv + q0.z, acc[3] * inv + q0.w};
  float4 o1 = {acc[4] * inv + q1v.x, acc[5] * inv + q1v.y,
               acc[6] * inv + q1v.z, acc[7] * inv + q1v.w};
  out[n * 4 + c8 * 2] = o0;
  out[n * 4 + c8 * 2 + 1] = o1;
}

extern "C" void kernel_launch(void* const* d_in, const int* in_sizes, int n_in,
                              void* d_out, int out_size, void* d_ws, size_t ws_size,
                              hipStream_t stream) {
  const float* x   = (const float*)d_in[0];
  const int* edge  = (const int*)d_in[1];
  const int* src   = edge;            // edge_index[0]
  const int* dst   = edge + N_EDGES;  // edge_index[1]
  const float* W1l = (const float*)d_in[2];
  const float* b1  = (const float*)d_in[3];
  const float* W1r = (const float*)d_in[4];
  const float* W2l = (const float*)d_in[5];
  const float* b2  = (const float*)d_in[6];
  const float* W2r = (const float*)d_in[7];
  float* out = (float*)d_out;

  // workspace layout (4-byte units; p1 base is 16B aligned)
  int* gcnt     = (int*)d_ws;          // 391 (padded to 512)
  int* rowstart = gcnt + 512;          // 100000
  int* cnt      = rowstart + N_NODES;  // 100000
  int* binned   = cnt + N_NODES;       // NBKT*CAP = 2001920
  int* csr      = binned + NBKT * CAP; // 2001920
  __half* p1    = (__half*)(csr + NBKT * CAP);  // 6.4M halves (12.8 MB)
  __half* q1h   = p1 + (size_t)N_NODES * 64;    // 6.4M halves (q1 -> h in place)
  __half* p2    = p1;                           // layer-2 reuse (p1 dead)
  float* q2     = (float*)(p1 + (size_t)N_NODES * 16);  // after p2 (3.2MB)

  hipMemsetAsync(gcnt, 0, NBKT * sizeof(int), stream);

  // 1: bin ∪ gemm1 (independent, one dispatch; bin blocks first)
  k_merged1<<<GB + G1B, 256, 0, stream>>>(src, dst, gcnt, binned,
                                          x, W1l, W1r, b1, p1, q1h);
  // 2: finalize ∪ fuse1 (bucket-per-block; csr written as side product)
  k_fuse1b<<<NBKT, 512, 0, stream>>>((const float4*)p1, gcnt, binned, csr,
                                     rowstart, cnt, (float4*)q1h);
  // 3: gemm2
  k_gemm2<<<(N_NODES + 127) / 128, 256, 0, stream>>>(q1h, W2l, W2r, b2, p2, q2);
  // 4: fuse2
  k_fuse2<<<(N_NODES + 127) / 128, 256, 0, stream>>>((const float4*)p2,
                                                     (const float4*)q2,
                                                     rowstart, cnt, csr,
                                                     (float4*)out);
}

// Round 13
// 188.979 us; speedup vs baseline: 1.2921x; 1.0215x over previous
//
#include <hip/hip_runtime.h>
#include <hip/hip_fp16.h>

#define N_NODES 100000
#define N_EDGES 1600000
#define IN_C 64
#define HID_C 64
#define OUT_C 16

#define BKT 256        // nodes per dst bucket
#define BSH 8          // dst >> 8 = bucket
#define NBKT 391       // ceil(100000/256)
#define CAP 5120       // slots per bucket (mean 4092, +16 sigma margin)
#define GB 512         // bin sub-blocks in merged pass 1
#define EPB 3125       // edges per bin block (512*3125 = 1.6M exact)
#define G1B 1563       // gemm1 sub-blocks = ceil(100000/64)

typedef _Float16 f16x8 __attribute__((ext_vector_type(8)));
typedef float f32x4 __attribute__((ext_vector_type(4)));
typedef float f32x16 __attribute__((ext_vector_type(16)));

// ---------------------------------------------------------------------------
// Merged pass 1: blocks [0,GB) bin edges; blocks [GB, GB+G1B) do GEMM1 (MFMA).
// ---------------------------------------------------------------------------
__global__ __launch_bounds__(256) void k_merged1(
    const int* __restrict__ src, const int* __restrict__ dst,
    int* __restrict__ gcnt, int* __restrict__ binned,
    const float* __restrict__ x, const float* __restrict__ Wl,
    const float* __restrict__ Wr, const float* __restrict__ b,
    __half* __restrict__ p, __half* __restrict__ q) {
  __shared__ _Float16 sA[64 * 68];    // gemm: [row][k]   | bin: h[] alias
  __shared__ _Float16 sW[128 * 68];   // gemm: [col][k]^T | bin: cur[] alias
  int t = threadIdx.x;

  if (blockIdx.x < GB) {
    int* h   = (int*)sA;
    int* cur = (int*)sW;
    for (int i = t; i < NBKT; i += 256) h[i] = 0;
    __syncthreads();
    int base = blockIdx.x * EPB;
    int end = base + EPB;
    for (int e = base + t; e < end; e += 256)
      atomicAdd(&h[dst[e] >> BSH], 1);
    __syncthreads();
    for (int i = t; i < NBKT; i += 256) {
      int c = h[i];
      int b0 = atomicAdd(&gcnt[i], c);   // reserve [b0, b0+c) in bucket i
      cur[i] = i * CAP + b0;
    }
    __syncthreads();
    for (int e = base + t; e < end; e += 256) {  // dst slice L1-hot
      int d = dst[e];
      int pos = atomicAdd(&cur[d >> BSH], 1);
      binned[pos] = (src[e] << BSH) | (d & (BKT - 1));
    }
    return;
  }

  int n0 = (blockIdx.x - GB) * 64;

  for (int f = t; f < 1024; f += 256) {
    int r = f >> 4, c4 = f & 15;
    int n = n0 + r;
    float4 v = {0.0f, 0.0f, 0.0f, 0.0f};
    if (n < N_NODES) v = *(const float4*)&x[(size_t)n * 64 + c4 * 4];
    union { _Float16 h[4]; float2 f2; } u;
    u.h[0] = (_Float16)v.x; u.h[1] = (_Float16)v.y;
    u.h[2] = (_Float16)v.z; u.h[3] = (_Float16)v.w;
    *(float2*)&sA[r * 68 + c4 * 4] = u.f2;
  }
  for (int f = t; f < 2048; f += 256) {
    int k = f >> 5, c4 = f & 31;
    float4 w = (c4 < 16) ? *(const float4*)&Wl[k * 64 + c4 * 4]
                         : *(const float4*)&Wr[k * 64 + (c4 - 16) * 4];
    int c = c4 * 4;
    sW[(c + 0) * 68 + k] = (_Float16)w.x;
    sW[(c + 1) * 68 + k] = (_Float16)w.y;
    sW[(c + 2) * 68 + k] = (_Float16)w.z;
    sW[(c + 3) * 68 + k] = (_Float16)w.w;
  }
  __syncthreads();

  int w = t >> 6, lane = t & 63;
  int m = lane & 31, half = lane >> 5;
  int rt = w & 1, cg = w >> 1;

  f32x16 acc[2];
#pragma unroll
  for (int r = 0; r < 16; ++r) { acc[0][r] = 0.0f; acc[1][r] = 0.0f; }

  const _Float16* pA = &sA[(rt * 32 + m) * 68 + half * 8];
  const _Float16* pB0 = &sW[(cg * 64 + m) * 68 + half * 8];
  const _Float16* pB1 = &sW[(cg * 64 + 32 + m) * 68 + half * 8];
#pragma unroll
  for (int kc = 0; kc < 4; ++kc) {
    union { f16x8 v; float2 f2[2]; } a, b0, b1;
    a.f2[0] = *(const float2*)(pA + kc * 16);
    a.f2[1] = *(const float2*)(pA + kc * 16 + 4);
    b0.f2[0] = *(const float2*)(pB0 + kc * 16);
    b0.f2[1] = *(const float2*)(pB0 + kc * 16 + 4);
    b1.f2[0] = *(const float2*)(pB1 + kc * 16);
    b1.f2[1] = *(const float2*)(pB1 + kc * 16 + 4);
    acc[0] = __builtin_amdgcn_mfma_f32_32x32x16_f16(a.v, b0.v, acc[0], 0, 0, 0);
    acc[1] = __builtin_amdgcn_mfma_f32_32x32x16_f16(a.v, b1.v, acc[1], 0, 0, 0);
  }

  if (cg == 0) {
#pragma unroll
    for (int tt = 0; tt < 2; ++tt) {
      int col = tt * 32 + m;
#pragma unroll
      for (int r = 0; r < 16; ++r) {
        int row = (r & 3) + 4 * half + 8 * (r >> 2);
        int n = n0 + rt * 32 + row;
        if (n < N_NODES) p[(size_t)n * 64 + col] = __float2half(acc[tt][r]);
      }
    }
  } else {
    float bias[2] = {b[m], b[32 + m]};
#pragma unroll
    for (int tt = 0; tt < 2; ++tt) {
      int col = tt * 32 + m;
#pragma unroll
      for (int r = 0; r < 16; ++r) {
        int row = (r & 3) + 4 * half + 8 * (r >> 2);
        int n = n0 + rt * 32 + row;
        if (n < N_NODES)
          q[(size_t)n * 64 + col] = __float2half(acc[tt][r] + bias[tt]);
      }
    }
  }
}

// ---------------------------------------------------------------------------
// Fuse1c (finalize ∪ fuse1 ∪ gemm2): one block per bucket, 1024 threads.
// Phase A: node histogram -> LDS scan -> scatter src into LDS lcsr;
//          export csr/rowstart/cnt for fuse2.
// Phase B: h = relu(mean_j p1[lcsr_j] + q1) -> fp16 into LDS sH (no global h).
// Phase C: MFMA 256x32 K=64: p2(fp16) = h @ W2l ; q2(fp32) = h @ W2r + b2.
//          16 waves x one 16-row tile, mfma_f32_16x16x32_f16.
// ---------------------------------------------------------------------------
__global__ __launch_bounds__(1024) void k_fuse1c(
    const float4* __restrict__ p1, const int* __restrict__ gcnt,
    const int* __restrict__ binned, const float* __restrict__ W2l,
    const float* __restrict__ W2r, const float* __restrict__ b2,
    const float4* __restrict__ q1, int* __restrict__ csr,
    int* __restrict__ rowstart, int* __restrict__ cnt,
    __half* __restrict__ p2, float* __restrict__ q2) {
  __shared__ int hcnt[BKT];
  __shared__ int hscan[BKT];
  __shared__ int cur[BKT];
  __shared__ int lcsr[CAP];          // 20 KB
  __shared__ _Float16 sH[256 * 68];  // 34.8 KB
  __shared__ _Float16 sW[32 * 68];   // 4.4 KB [col][k]^T: 0-15 W2l, 16-31 W2r
  int b = blockIdx.x;
  int t = threadIdx.x;

  // stage W2^T (512 half4 chunks)
  if (t < 512) {
    int k = t >> 3, c4v = t & 7;
    float4 w = (c4v < 4) ? *(const float4*)&W2l[k * 16 + c4v * 4]
                         : *(const float4*)&W2r[k * 16 + (c4v - 4) * 4];
    int c = c4v * 4;
    sW[(c + 0) * 68 + k] = (_Float16)w.x;
    sW[(c + 1) * 68 + k] = (_Float16)w.y;
    sW[(c + 2) * 68 + k] = (_Float16)w.z;
    sW[(c + 3) * 68 + k] = (_Float16)w.w;
  }
  if (t < BKT) hcnt[t] = 0;
  __syncthreads();

  // ---- Phase A ----
  int start = b * CAP;
  int total = gcnt[b];
  for (int i = t; i < total; i += 1024)
    atomicAdd(&hcnt[binned[start + i] & (BKT - 1)], 1);
  __syncthreads();
  int v = 0;
  if (t < BKT) {
    v = hcnt[t];
    hscan[t] = v;
  }
  __syncthreads();
  for (int st = 1; st < 256; st <<= 1) {
    int a = 0;
    if (t < BKT && t >= st) a = hscan[t - st];
    __syncthreads();
    if (t < BKT) hscan[t] += a;
    __syncthreads();
  }
  if (t < BKT) {
    cur[t] = hscan[t] - v;          // local exclusive start
    int n = (b << BSH) + t;
    if (n < N_NODES) {
      rowstart[n] = start + hscan[t] - v;
      cnt[n] = v;
    }
  }
  __syncthreads();
  for (int i = t; i < total; i += 1024) {
    int vv = binned[start + i];
    int pos = atomicAdd(&cur[vv & (BKT - 1)], 1);
    lcsr[pos] = vv >> BSH;
  }
  __syncthreads();
  for (int i = t; i < total; i += 1024) csr[start + i] = lcsr[i];  // for fuse2

  // ---- Phase B: aggregate + relu -> sH (fp16) ----
  int g = t >> 3, c4 = t & 7;
  for (int r = g; r < BKT; r += 128) {
    int n = (b << BSH) + r;
    if (n >= N_NODES) continue;
    int deg = hcnt[r];
    int row = hscan[r] - deg;  // local start in lcsr
    float acc[8];
#pragma unroll
    for (int m = 0; m < 8; ++m) acc[m] = 0.0f;
    int j = 0;
    for (; j + 8 <= deg; j += 8) {
      int idx[8];
#pragma unroll
      for (int u = 0; u < 8; ++u) idx[u] = lcsr[row + j + u];
      float4 av[8];
#pragma unroll
      for (int u = 0; u < 8; ++u) av[u] = p1[idx[u] * 8 + c4];
#pragma unroll
      for (int u = 0; u < 8; ++u) {
        const __half2* h = (const __half2*)&av[u];
#pragma unroll
        for (int m = 0; m < 4; ++m) {
          float2 f = __half22float2(h[m]);
          acc[2 * m] += f.x;
          acc[2 * m + 1] += f.y;
        }
      }
    }
    for (; j < deg; ++j) {
      float4 a = p1[lcsr[row + j] * 8 + c4];
      const __half2* h = (const __half2*)&a;
#pragma unroll
      for (int m = 0; m < 4; ++m) {
        float2 f = __half22float2(h[m]);
        acc[2 * m] += f.x;
        acc[2 * m + 1] += f.y;
      }
    }
    float inv = 1.0f / fmaxf((float)deg, 1.0f);
    float4 qv = q1[n * 8 + c4];
    __half2* qh = (__half2*)&qv;
    union { __half2 h2[2]; float2 f2; } u01, u23;
#pragma unroll
    for (int m = 0; m < 2; ++m) {
      float2 f = __half22float2(qh[m]);
      float2 s;
      s.x = fmaxf(acc[2 * m] * inv + f.x, 0.0f);
      s.y = fmaxf(acc[2 * m + 1] * inv + f.y, 0.0f);
      u01.h2[m] = __float22half2_rn(s);
    }
#pragma unroll
    for (int m = 2; m < 4; ++m) {
      float2 f = __half22float2(qh[m]);
      float2 s;
      s.x = fmaxf(acc[2 * m] * inv + f.x, 0.0f);
      s.y = fmaxf(acc[2 * m + 1] * inv + f.y, 0.0f);
      u23.h2[m - 2] = __float22half2_rn(s);
    }
    *(float2*)&sH[r * 68 + c4 * 8] = u01.f2;
    *(float2*)&sH[r * 68 + c4 * 8 + 4] = u23.f2;
  }
  __syncthreads();

  // ---- Phase C: 16 waves, one 16-row tile each, cols 0-15->p2, 16-31->q2 ----
  int wv = t >> 6, lane = t & 63;
  int n16 = lane & 15, quad = lane >> 4;
  f32x4 aP, aQ;
#pragma unroll
  for (int r = 0; r < 4; ++r) { aP[r] = 0.0f; aQ[r] = 0.0f; }
  const _Float16* pA = &sH[(wv * 16 + n16) * 68 + quad * 8];
  const _Float16* pBP = &sW[n16 * 68 + quad * 8];
  const _Float16* pBQ = &sW[(16 + n16) * 68 + quad * 8];
#pragma unroll
  for (int kc = 0; kc < 2; ++kc) {
    union { f16x8 v; float2 f2[2]; } a, bp, bq;
    a.f2[0] = *(const float2*)(pA + kc * 32);
    a.f2[1] = *(const float2*)(pA + kc * 32 + 4);
    bp.f2[0] = *(const float2*)(pBP + kc * 32);
    bp.f2[1] = *(const float2*)(pBP + kc * 32 + 4);
    bq.f2[0] = *(const float2*)(pBQ + kc * 32);
    bq.f2[1] = *(const float2*)(pBQ + kc * 32 + 4);
    aP = __builtin_amdgcn_mfma_f32_16x16x32_f16(a.v, bp.v, aP, 0, 0, 0);
    aQ = __builtin_amdgcn_mfma_f32_16x16x32_f16(a.v, bq.v, aQ, 0, 0, 0);
  }
  float bias = b2[n16];
#pragma unroll
  for (int r = 0; r < 4; ++r) {
    int row = wv * 16 + quad * 4 + r;
    int n = (b << BSH) + row;
    if (n < N_NODES) {
      p2[(size_t)n * 16 + n16] = __float2half(aP[r]);
      q2[(size_t)n * 16 + n16] = aQ[r] + bias;
    }
  }
}

// ---------------------------------------------------------------------------
// Fuse 2: out[n] = mean_j p2[csr_j] + q2[n].
// float4 gathers, 2 lanes/node, 8-deep unroll.
// ---------------------------------------------------------------------------
__global__ __launch_bounds__(256) void k_fuse2(
    const float4* __restrict__ p2, const float4* __restrict__ q2,
    const int* __restrict__ rowstart, const int* __restrict__ cnt,
    const int* __restrict__ csr, float4* __restrict__ out) {
  int t = threadIdx.x;
  int n = blockIdx.x * 128 + (t >> 1);
  if (n >= N_NODES) return;
  int c8 = t & 1;
  int row = rowstart[n];
  int deg = cnt[n];
  float acc[8];
#pragma unroll
  for (int m = 0; m < 8; ++m) acc[m] = 0.0f;
  int j = 0;
  for (; j + 8 <= deg; j += 8) {
    int idx[8];
#pragma unroll
    for (int u = 0; u < 8; ++u) idx[u] = csr[row + j + u];
    float4 av[8];
#pragma unroll
    for (int u = 0; u < 8; ++u) av[u] = p2[idx[u] * 2 + c8];
#pragma unroll
    for (int u = 0; u < 8; ++u) {
      const __half2* h = (const __half2*)&av[u];
#pragma unroll
      for (int m = 0; m < 4; ++m) {
        float2 f = __half22float2(h[m]);
        acc[2 * m] += f.x;
        acc[2 * m + 1] += f.y;
      }
    }
  }
  for (; j < deg; ++j) {
    float4 a = p2[csr[row + j] * 2 + c8];
    const __half2* h = (const __half2*)&a;
#pragma unroll
    for (int m = 0; m < 4; ++m) {
      float2 f = __half22float2(h[m]);
      acc[2 * m] += f.x;
      acc[2 * m + 1] += f.y;
    }
  }
  float inv = 1.0f / fmaxf((float)deg, 1.0f);
  float4 q0 = q2[n * 4 + c8 * 2];
  float4 q1v = q2[n * 4 + c8 * 2 + 1];
  float4 o0 = {acc[0] * inv + q0.x, acc[1] * inv + q0.y,
               acc[2] * inv + q0.z, acc[3] * inv + q0.w};
  float4 o1 = {acc[4] * inv + q1v.x, acc[5] * inv + q1v.y,
               acc[6] * inv + q1v.z, acc[7] * inv + q1v.w};
  out[n * 4 + c8 * 2] = o0;
  out[n * 4 + c8 * 2 + 1] = o1;
}

extern "C" void kernel_launch(void* const* d_in, const int* in_sizes, int n_in,
                              void* d_out, int out_size, void* d_ws, size_t ws_size,
                              hipStream_t stream) {
  const float* x   = (const float*)d_in[0];
  const int* edge  = (const int*)d_in[1];
  const int* src   = edge;            // edge_index[0]
  const int* dst   = edge + N_EDGES;  // edge_index[1]
  const float* W1l = (const float*)d_in[2];
  const float* b1  = (const float*)d_in[3];
  const float* W1r = (const float*)d_in[4];
  const float* W2l = (const float*)d_in[5];
  const float* b2  = (const float*)d_in[6];
  const float* W2r = (const float*)d_in[7];
  float* out = (float*)d_out;

  // workspace layout (4-byte units; fp16 bases 16B aligned)
  int* gcnt     = (int*)d_ws;          // 391 (padded to 512)
  int* rowstart = gcnt + 512;          // 100000
  int* cnt      = rowstart + N_NODES;  // 100000
  int* binned   = cnt + N_NODES;       // NBKT*CAP = 2001920
  int* csr      = binned + NBKT * CAP; // 2001920
  __half* p1    = (__half*)(csr + NBKT * CAP);  // 6.4M halves (12.8 MB)
  __half* q1    = p1 + (size_t)N_NODES * 64;    // 6.4M halves (12.8 MB)
  __half* p2    = q1 + (size_t)N_NODES * 64;    // 1.6M halves (3.2 MB)
  float* q2     = (float*)(p2 + (size_t)N_NODES * 16);  // 1.6M floats (6.4 MB)

  hipMemsetAsync(gcnt, 0, NBKT * sizeof(int), stream);

  // 1: bin ∪ gemm1 (independent, one dispatch; bin blocks first)
  k_merged1<<<GB + G1B, 256, 0, stream>>>(src, dst, gcnt, binned,
                                          x, W1l, W1r, b1, p1, q1);
  // 2: finalize ∪ fuse1 ∪ gemm2 (bucket-per-block, 1024 thr)
  k_fuse1c<<<NBKT, 1024, 0, stream>>>((const float4*)p1, gcnt, binned,
                                      W2l, W2r, b2, (const float4*)q1,
                                      csr, rowstart, cnt, p2, q2);
  // 3: fuse2
  k_fuse2<<<(N_NODES + 127) / 128, 256, 0, stream>>>((const float4*)p2,
                                                     (const float4*)q2,
                                                     rowstart, cnt, csr,
                                                     (float4*)out);
}